// Round 3
// baseline (553.949 us; speedup 1.0000x reference)
//
#include <hip/hip_runtime.h>
#include <cstdint>
#include <cstddef>

// ---------------------------------------------------------------------------
// QuantCrossAttention, MI355X/gfx950.  B=2 N=4096 L=512 C=2048 H=16 D=128.
// - int8 quant replicated bit-exactly (IEEE div, rintf=RNE, max-chain)
// - w8a8 GEMMs on TRUE i8 MFMA (mfma_i32_16x16x64_i8), operands XOR-swizzled
//   in GLOBAL layout so global_load_lds stages verbatim.
// - fp32 GEMMs (K/V proj, QK^T, PV) via bf16 hi/lo split, 3 MFMA terms
// R6: T14 issue-early/write-late staging in attn; 2-phase dbuf in gemm_i8.
// R7: attn reg diet (2 blocks/CU) + T1 XCD swizzle everywhere.
// R8 (theory: attn is LDS-pipe-paced at ~65% busy; the residual ~35% is the
//     2-barrier lockstep write-bubble.  Make it a 1-barrier dbuf pipeline):
//   * attn_k: 1024-thr / 16-wave / 256-row single block per CU.  ks AND vt
//     double-buffered (LDS 104448 B); prefetch distance 2: regs hold chunk
//     i+1, written to buf^1 at top of chunk i while compute reads buf[i&1]
//     => ONE __syncthreads per chunk, staging writes fully overlapped.
//     vt pad dropped (XOR swizzle already spreads banks).  Per-wave math,
//     chunk order, and MFMA sequence unchanged => bit-identical output.
// ---------------------------------------------------------------------------

typedef __bf16 bf16;
typedef __bf16 bf16x8 __attribute__((ext_vector_type(8)));
typedef __bf16 bf16x4 __attribute__((ext_vector_type(4)));
typedef float  f32x4  __attribute__((ext_vector_type(4)));
typedef int    i32x4  __attribute__((ext_vector_type(4)));

#define DEV __device__ __forceinline__

static constexpr int CB = 2;
static constexpr int CN = 4096;
static constexpr int CL = 512;
static constexpr int CC = 2048;
static constexpr int CH = 16;
static constexpr int CD = 128;
static constexpr int TOK = CB * CN;  // 8192 tokens
static constexpr int LR  = CB * CL;  // 1024 cond rows

DEV void gl_lds16(const void* g, void* l) {
  __builtin_amdgcn_global_load_lds(
      (const __attribute__((address_space(1))) unsigned int*)g,
      (__attribute__((address_space(3))) unsigned int*)l, 16, 0, 0);
}

DEV f32x4 mfma16(bf16x8 a, bf16x8 b, f32x4 c) {
  return __builtin_amdgcn_mfma_f32_16x16x32_bf16(a, b, c, 0, 0, 0);
}

DEV i32x4 mfma_i8(i32x4 a, i32x4 b, i32x4 c) {
  return __builtin_amdgcn_mfma_i32_16x16x64_i8(a, b, c, 0, 0, 0);
}

// --------- per-row symmetric int8 quant -> swizzled int8 + scale ------------
__global__ __launch_bounds__(256) void quant_rows_i8(
    const float* __restrict__ in, signed char* __restrict__ q,
    float* __restrict__ scale)
{
  const int r = blockIdx.x, t = threadIdx.x;
  const float* x = in + (size_t)r * CC;
  const float4 v0 = ((const float4*)x)[2 * t];
  const float4 v1 = ((const float4*)x)[2 * t + 1];
  float m = fmaxf(fmaxf(fmaxf(fabsf(v0.x), fabsf(v0.y)), fmaxf(fabsf(v0.z), fabsf(v0.w))),
                  fmaxf(fmaxf(fabsf(v1.x), fabsf(v1.y)), fmaxf(fabsf(v1.z), fabsf(v1.w))));
#pragma unroll
  for (int off = 32; off > 0; off >>= 1) m = fmaxf(m, __shfl_xor(m, off));
  __shared__ float sm[4];
  if ((t & 63) == 0) sm[t >> 6] = m;
  __syncthreads();
  m = fmaxf(fmaxf(sm[0], sm[1]), fmaxf(sm[2], sm[3]));
  const float s = fmaxf(m / 127.0f, 1e-8f);   // IEEE divide: bit-matches np
  if (t == 0) scale[r] = s;
  const float a[8] = {v0.x, v0.y, v0.z, v0.w, v1.x, v1.y, v1.z, v1.w};
  int2 pk;
  int lo = 0, hi = 0;
#pragma unroll
  for (int j = 0; j < 4; j++) {
    const int b0 = (int)fminf(fmaxf(rintf(a[j]     / s), -127.f), 127.f);
    const int b1 = (int)fminf(fmaxf(rintf(a[4 + j] / s), -127.f), 127.f);
    lo |= (b0 & 255) << (8 * j);
    hi |= (b1 & 255) << (8 * j);
  }
  pk.x = lo; pk.y = hi;
  const int c0 = t * 8;
  const int f = (r >> 1) & 3;
  const int pos = (c0 & ~63) | ((((c0 >> 4) & 3) ^ f) << 4) | (c0 & 15);
  *(int2*)&q[(size_t)r * CC + pos] = pk;
}

// --------- fp32 -> bf16 hi/lo split ----------------------------------------
__global__ __launch_bounds__(256) void split_pair_k(
    const float* __restrict__ in, bf16* __restrict__ hi, bf16* __restrict__ lo)
{
  const size_t i = (size_t)blockIdx.x * 256 + threadIdx.x;  // float4 index
  const float4 v = ((const float4*)in)[i];
  const float a[4] = {v.x, v.y, v.z, v.w};
  bf16x4 h4, l4;
#pragma unroll
  for (int j = 0; j < 4; j++) {
    bf16 h = (bf16)a[j];
    h4[j] = h;
    l4[j] = (bf16)(a[j] - (float)h);
  }
  ((bf16x4*)hi)[i] = h4;
  ((bf16x4*)lo)[i] = l4;
}

// --------- (x + bias[col]) -> bf16 hi/lo split (K path) ---------------------
__global__ __launch_bounds__(256) void bias_split_k(
    const float* __restrict__ in, const float* __restrict__ bias,
    bf16* __restrict__ hi, bf16* __restrict__ lo)
{
  const size_t i = (size_t)blockIdx.x * 256 + threadIdx.x;  // float4 index
  const float4 v = ((const float4*)in)[i];
  const float4 bb = ((const float4*)bias)[i & (CC / 4 - 1)];
  const float a[4] = {v.x + bb.x, v.y + bb.y, v.z + bb.z, v.w + bb.w};
  bf16x4 h4, l4;
#pragma unroll
  for (int j = 0; j < 4; j++) {
    bf16 h = (bf16)a[j];
    h4[j] = h;
    l4[j] = (bf16)(a[j] - (float)h);
  }
  ((bf16x4*)hi)[i] = h4;
  ((bf16x4*)lo)[i] = l4;
}

// --------- (V + bias) -> transpose to [b,h,d,l] -> bf16 hi/lo split ---------
__global__ __launch_bounds__(256) void bias_split_vt_k(
    const float* __restrict__ Vf, const float* __restrict__ bias,
    bf16* __restrict__ vth, bf16* __restrict__ vtl)
{
  __shared__ float tile[32][33];
  const int t = threadIdx.x;
  const int l0 = blockIdx.x * 32, d0 = blockIdx.y * 32, bh = blockIdx.z;
  const int b = bh >> 4, h = bh & 15;
  const int r = t >> 3, c4 = (t & 7) * 4;
  const float4 v = *(const float4*)&Vf[((size_t)b * CL + l0 + r) * CC + h * CD + d0 + c4];
  const float4 bb = *(const float4*)&bias[h * CD + d0 + c4];
  tile[r][c4 + 0] = v.x + bb.x;
  tile[r][c4 + 1] = v.y + bb.y;
  tile[r][c4 + 2] = v.z + bb.z;
  tile[r][c4 + 3] = v.w + bb.w;
  __syncthreads();
  bf16x4 h4, l4;
#pragma unroll
  for (int j = 0; j < 4; j++) {
    const float a = tile[c4 + j][r];   // transposed read, pad-33 => <=2-way
    const bf16 hh = (bf16)a;
    h4[j] = hh;
    l4[j] = (bf16)(a - (float)hh);
  }
  const size_t o = ((size_t)bh * CD + d0 + r) * CL + l0 + c4;
  *(bf16x4*)&vth[o] = h4;
  *(bf16x4*)&vtl[o] = l4;
}

// --------- int8 GEMM, A[M,K] * B[Nd,K]^T, both K-major, pre-swizzled --------
// 2-phase double-buffered pipeline (one barrier per K-step) + T1 XCD swizzle.
template <int MODE>
__global__ __launch_bounds__(256) void gemm_i8(
    const signed char* __restrict__ A, const signed char* __restrict__ B,
    float* __restrict__ out0, bf16* __restrict__ outH, bf16* __restrict__ outL,
    const float* __restrict__ rowS, const float* __restrict__ colS,
    const float* __restrict__ bias, const int Nd, const int K)
{
  __shared__ signed char sA[2][128 * 64] __attribute__((aligned(16)));
  __shared__ signed char sB[2][128 * 64] __attribute__((aligned(16)));
  const int t = threadIdx.x;
  int lin = blockIdx.y * 16 + blockIdx.x;          // grid = (16, 64) = 1024
  lin = (lin & 7) * 128 + (lin >> 3);              // XCD-contiguous logical id
  const int m0 = (lin >> 4) * 128, n0 = (lin & 15) * 128;
  const int srow = t >> 2, scol = (t & 3) * 16;   // 64 rows/instr, 16B/lane
  const signed char* aP = A + (size_t)(m0 + srow) * K + scol;
  const signed char* bP = B + (size_t)(n0 + srow) * K + scol;
  const int lane = t & 63, wave = t >> 6;
  const int wm = (wave >> 1) * 64, wn = (wave & 1) * 64;
  const int quad = lane >> 4, l16 = lane & 15;
  i32x4 acc[4][4] = {};

  // prologue: stage k-block 0 into buffer 0
  gl_lds16(aP,                  &sA[0][t * 16]);
  gl_lds16(aP + (size_t)64 * K, &sA[0][4096 + t * 16]);
  gl_lds16(bP,                  &sB[0][t * 16]);
  gl_lds16(bP + (size_t)64 * K, &sB[0][4096 + t * 16]);
  __syncthreads();

  int cur = 0;
  for (int kb = 0; kb < K; kb += 64) {
    const int nx = kb + 64;
    if (nx < K) {   // stage next k-block into the other buffer (async)
      gl_lds16(aP + nx,                  &sA[cur ^ 1][t * 16]);
      gl_lds16(aP + nx + (size_t)64 * K, &sA[cur ^ 1][4096 + t * 16]);
      gl_lds16(bP + nx,                  &sB[cur ^ 1][t * 16]);
      gl_lds16(bP + nx + (size_t)64 * K, &sB[cur ^ 1][4096 + t * 16]);
    }
    i32x4 fa[4], fb[4];
#pragma unroll
    for (int i = 0; i < 4; i++) {
      const int ra = wm + i * 16 + l16;
      const int rb = wn + i * 16 + l16;
      fa[i] = *(const i32x4*)&sA[cur][ra * 64 + (quad ^ ((ra >> 1) & 3)) * 16];
      fb[i] = *(const i32x4*)&sB[cur][rb * 64 + (quad ^ ((rb >> 1) & 3)) * 16];
    }
#pragma unroll
    for (int mt = 0; mt < 4; mt++)
#pragma unroll
      for (int nt = 0; nt < 4; nt++)
        acc[mt][nt] = mfma_i8(fa[mt], fb[nt], acc[mt][nt]);
    __syncthreads();   // drains vmcnt(0): buf^1 staged; lgkm: buf reads done
    cur ^= 1;
  }

  // epilogue: C/D layout col=lane&15, row=quad*4+reg (shape-determined)
#pragma unroll
  for (int mt = 0; mt < 4; mt++)
#pragma unroll
    for (int nt = 0; nt < 4; nt++)
#pragma unroll
      for (int rg = 0; rg < 4; rg++) {
        const int mr = m0 + wm + mt * 16 + quad * 4 + rg;
        const int nc = n0 + wn + nt * 16 + l16;
        const float a = (float)acc[mt][nt][rg];
        const float sc = rowS[mr] * colS[nc];   // (sx*sw) first: matches np
        const float v = a * sc + bias[nc];
        if (MODE == 0) {
          out0[(size_t)mr * Nd + nc] = v;
        } else {
          const bf16 h = (bf16)v;
          outH[(size_t)mr * Nd + nc] = h;
          outL[(size_t)mr * Nd + nc] = (bf16)(v - (float)h);
        }
      }
}

// --------- bf16-split GEMM (K/V projections only) ---------------------------
__global__ __launch_bounds__(256) void gemm_kv(
    const bf16* __restrict__ Ah, const bf16* __restrict__ Al,
    const bf16* __restrict__ B0h, const bf16* __restrict__ B0l,
    const bf16* __restrict__ B1h, const bf16* __restrict__ B1l,
    float* __restrict__ out0, float* __restrict__ out1,
    const int Nd, const int K, const int kLen)
{
  __shared__ bf16 sAh[128 * 32] __attribute__((aligned(16)));
  __shared__ bf16 sBh[128 * 32] __attribute__((aligned(16)));
  __shared__ bf16 sAl[128 * 32] __attribute__((aligned(16)));
  __shared__ bf16 sBl[128 * 32] __attribute__((aligned(16)));
  const int t = threadIdx.x;
  int lin = (blockIdx.z * 8 + blockIdx.y) * 16 + blockIdx.x;  // (16,8,8) grid
  lin = (lin & 7) * 128 + (lin >> 3);                         // XCD swizzle
  const int bx = lin & 15, by = (lin >> 4) & 7, bz = lin >> 7;
  const int kv = bz >> 2, chunk = bz & 3;
  const bf16* Bh = kv ? B1h : B0h;
  const bf16* Bl = kv ? B1l : B0l;
  float* outF = kv ? out1 : out0;
  const int m0 = by * 128, n0 = bx * 128;
  const int k0 = chunk * kLen;
  const int srow = t >> 2, scol = (t & 3) * 8;
  const bf16* aP  = Ah + (size_t)(m0 + srow) * K + k0 + scol;
  const bf16* bP  = Bh + (size_t)(n0 + srow) * K + k0 + scol;
  const bf16* aPl = Al + (size_t)(m0 + srow) * K + k0 + scol;
  const bf16* bPl = Bl + (size_t)(n0 + srow) * K + k0 + scol;
  const int lane = t & 63, wave = t >> 6;
  const int wm = (wave >> 1) * 64, wn = (wave & 1) * 64;
  const int quad = lane >> 4, l16 = lane & 15;
  f32x4 acc[4][4] = {};

  for (int kb = 0; kb < kLen; kb += 32) {
    __syncthreads();
    gl_lds16(aP + kb,                   &sAh[t * 8]);
    gl_lds16(aP + kb + (size_t)64 * K,  &sAh[2048 + t * 8]);
    gl_lds16(bP + kb,                   &sBh[t * 8]);
    gl_lds16(bP + kb + (size_t)64 * K,  &sBh[2048 + t * 8]);
    gl_lds16(aPl + kb,                  &sAl[t * 8]);
    gl_lds16(aPl + kb + (size_t)64 * K, &sAl[2048 + t * 8]);
    gl_lds16(bPl + kb,                  &sBl[t * 8]);
    gl_lds16(bPl + kb + (size_t)64 * K, &sBl[2048 + t * 8]);
    __syncthreads();
    bf16x8 fa[4], fb[4], fal[4], fbl[4];
#pragma unroll
    for (int i = 0; i < 4; i++) {
      fa[i]  = *(const bf16x8*)&sAh[(wm + i * 16 + l16) * 32 + quad * 8];
      fb[i]  = *(const bf16x8*)&sBh[(wn + i * 16 + l16) * 32 + quad * 8];
      fal[i] = *(const bf16x8*)&sAl[(wm + i * 16 + l16) * 32 + quad * 8];
      fbl[i] = *(const bf16x8*)&sBl[(wn + i * 16 + l16) * 32 + quad * 8];
    }
#pragma unroll
    for (int mt = 0; mt < 4; mt++)
#pragma unroll
      for (int nt = 0; nt < 4; nt++) {
        f32x4 c = acc[mt][nt];
        c = mfma16(fa[mt],  fb[nt],  c);
        c = mfma16(fa[mt],  fbl[nt], c);
        c = mfma16(fal[mt], fb[nt],  c);
        acc[mt][nt] = c;
      }
  }

#pragma unroll
  for (int mt = 0; mt < 4; mt++)
#pragma unroll
    for (int nt = 0; nt < 4; nt++)
#pragma unroll
      for (int rg = 0; rg < 4; rg++) {
        const int mr = m0 + wm + mt * 16 + quad * 4 + rg;
        const int nc = n0 + wn + nt * 16 + l16;
        atomicAdd(&outF[(size_t)mr * Nd + nc], acc[mt][nt][rg]);
      }
}

// --------- flash attention, split-bf16, MAX-FREE softmax --------------------
// R8: 1024 thr / 16 waves / 256 Q rows; ONE block per CU.  ks+vt both
// double-buffered; prefetch distance 2; ONE barrier per chunk.  Per-wave
// math identical to R7 (bit-identical output).
__global__ __launch_bounds__(1024, 4) void attn_k(
    const bf16* __restrict__ qh, const bf16* __restrict__ ql,
    const bf16* __restrict__ kh, const bf16* __restrict__ kl,
    const bf16* __restrict__ vth, const bf16* __restrict__ vtl,
    const float* __restrict__ mask, float* __restrict__ O)
{
  // arena: ks [2][2][32][136] (34816 B) | vt [2][2][128][32] (32768 B)
  //        | ps [16][16][36] (36864 B)  = 104448 B
  __shared__ char arena[34816 + 32768 + 36864] __attribute__((aligned(16)));
  bf16 (*ksb)[2][32][136] = (bf16 (*)[2][32][136])arena;           // [dbuf][hilo]
  bf16 (*vtb)[2][128][32] = (bf16 (*)[2][128][32])(arena + 34816); // [dbuf][hilo]
  float (*ps)[16][36] = (float (*)[16][36])(arena + 34816 + 32768);
  const int t = threadIdx.x, lane = t & 63, w = t >> 6;   // w in 0..15
  const int quad = lane >> 4, l16 = lane & 15;
  int lin = (blockIdx.z * 16 + blockIdx.y) * 16 + blockIdx.x;  // (16,16,2)=512
  lin = (lin & 7) * 64 + (lin >> 3);                           // XCD swizzle
  const int n0 = (lin & 15) * 256;
  const int h  = (lin >> 4) & 15;
  const int b  = lin >> 8;
  const int bh = b * CH + h;
  const size_t qrow0 = (size_t)b * CN + n0;
  const float* mrow_base = mask + ((size_t)b * CN + n0 + w * 16 + quad * 4) * CL;

  // ---- staging-lane geometry (1024 thr: plane = hi/lo by t>>9) ----
  const int pl   = t >> 9;                       // 0 = hi, 1 = lo
  const int krow = (t >> 4) & 31, ksg = t & 15;  // K: 32 l-rows x 128 d, 16B
  const int vrow = (t >> 2) & 127, vsg = t & 3;  // V^T: 128 d-rows x 32 l, 16B
  const bf16* kPsrc = pl ? kl : kh;
  const bf16* vPsrc = pl ? vtl : vth;
  const int vc = (vsg ^ ((vrow >> 3) & 3)) * 8;  // XOR chunk swizzle (fixed)
  uint4 kr, vr;
  // chunk-0 prefetch (overlaps Q preamble)
  kr = *(const uint4*)(kPsrc + ((size_t)b * CL + krow) * CC + h * CD + ksg * 8);
  vr = *(const uint4*)(vPsrc + ((size_t)bh * CD + vrow) * CL + vsg * 8);

  // ---- Q fragments into registers (staged via arena for coalescing) ----
  bf16x8 qfh[4], qfl[4];
  {
    bf16* qs = (bf16*)arena;   // 256 rows x 136 = 69632 B (ps not yet live)
    const int row = t >> 2, sg = t & 3;
    {
      const bf16* src = qh + (qrow0 + row) * CC + h * CD + sg * 32;
      bf16* dst = qs + row * 136 + sg * 32;
#pragma unroll
      for (int j = 0; j < 4; j++) ((uint4*)dst)[j] = ((const uint4*)src)[j];
    }
    __syncthreads();
#pragma unroll
    for (int s = 0; s < 4; s++)
      qfh[s] = *(const bf16x8*)&qs[(w * 16 + l16) * 136 + s * 32 + quad * 8];
    __syncthreads();
    {
      const bf16* src = ql + (qrow0 + row) * CC + h * CD + sg * 32;
      bf16* dst = qs + row * 136 + sg * 32;
#pragma unroll
      for (int j = 0; j < 4; j++) ((uint4*)dst)[j] = ((const uint4*)src)[j];
    }
    __syncthreads();
#pragma unroll
    for (int s = 0; s < 4; s++)
      qfl[s] = *(const bf16x8*)&qs[(w * 16 + l16) * 136 + s * 32 + quad * 8];
    __syncthreads();   // qs reads done; arena now owned by ks/vt/ps
  }

  // ---- pipeline prologue: write chunk0 -> buf0; load chunk1 regs ----
  *(uint4*)&ksb[0][pl][krow][ksg * 8] = kr;
  *(uint4*)&vtb[0][pl][vrow][vc] = vr;
  kr = *(const uint4*)(kPsrc + ((size_t)b * CL + 32 + krow) * CC + h * CD + ksg * 8);
  vr = *(const uint4*)(vPsrc + ((size_t)bh * CD + vrow) * CL + 32 + vsg * 8);

  f32x4 oacc[8] = {};
  f32x4 suma = {};          // row-sum accumulator (MFMA ones-trick)
  const bf16 one = (bf16)1.0f;
  const bf16x8 ones = {one, one, one, one, one, one, one, one};
  const float isd = 0.08838834764831845f;   // np.float32(1/sqrt(128))

  for (int ci = 0; ci < CL / 32; ci++) {
    const int cur = ci & 1;
    __syncthreads();   // closes chunk ci-1 reads of buf^1; buf[cur] visible
    // ---- write-late: chunk ci+1 regs -> other buffer (overlaps compute) --
    if (ci + 1 < CL / 32) {
      *(uint4*)&ksb[cur ^ 1][pl][krow][ksg * 8] = kr;
      *(uint4*)&vtb[cur ^ 1][pl][vrow][vc] = vr;
    }
    // ---- issue-early: chunk ci+2 prefetch (full chunk of latency cover) --
    if (ci + 2 < CL / 32) {
      const int lcn = (ci + 2) * 32;
      kr = *(const uint4*)(kPsrc + ((size_t)b * CL + lcn + krow) * CC + h * CD + ksg * 8);
      vr = *(const uint4*)(vPsrc + ((size_t)bh * CD + vrow) * CL + lcn + vsg * 8);
    }
    // ---- current-chunk mask loads (QK covers the latency) ----------------
    const int lc = ci * 32;
    float mcur[2][4];
#pragma unroll
    for (int rg = 0; rg < 4; rg++) {
      const float* mrp = mrow_base + (size_t)rg * CL + lc;
      mcur[0][rg] = mrp[l16];
      mcur[1][rg] = mrp[16 + l16];
    }

    // ---- S = Q K^T (split, 3 terms), two 16x16 l-tiles -------------------
    f32x4 sacc[2] = {};
    __builtin_amdgcn_s_setprio(1);
#pragma unroll
    for (int s = 0; s < 4; s++) {
#pragma unroll
      for (int lt = 0; lt < 2; lt++) {
        bf16x8 kbh = *(const bf16x8*)&ksb[cur][0][lt * 16 + l16][s * 32 + quad * 8];
        bf16x8 kbl = *(const bf16x8*)&ksb[cur][1][lt * 16 + l16][s * 32 + quad * 8];
        sacc[lt] = mfma16(qfh[s], kbh, sacc[lt]);
        sacc[lt] = mfma16(qfh[s], kbl, sacc[lt]);
        sacc[lt] = mfma16(qfl[s], kbh, sacc[lt]);
      }
    }
    __builtin_amdgcn_s_setprio(0);

    // ---- MAX-FREE softmax: u = exp(s*isd + mask); sum rides MFMA ---------
    float u[2][4];
#pragma unroll
    for (int rg = 0; rg < 4; rg++) {
      u[0][rg] = __expf(sacc[0][rg] * isd + mcur[0][rg]);
      u[1][rg] = __expf(sacc[1][rg] * isd + mcur[1][rg]);
    }

    // ---- P: C-layout -> A-layout via wave-private LDS round-trip ---------
#pragma unroll
    for (int lt = 0; lt < 2; lt++)
#pragma unroll
      for (int rg = 0; rg < 4; rg++)
        ps[w][quad * 4 + rg][lt * 16 + l16] = u[lt][rg];
    const float4 p0 = *(const float4*)&ps[w][l16][quad * 8];
    const float4 p1 = *(const float4*)&ps[w][l16][quad * 8 + 4];
    const float pv[8] = {p0.x, p0.y, p0.z, p0.w, p1.x, p1.y, p1.z, p1.w};
    bf16x8 ph, plv;
#pragma unroll
    for (int j = 0; j < 8; j++) {
      bf16 hh = (bf16)pv[j];
      ph[j] = hh;
      plv[j] = (bf16)(pv[j] - (float)hh);
    }

    // ---- O += P V (split, 3 terms) + row-sum channel ---------------------
    suma = mfma16(ph, ones, suma);
    suma = mfma16(plv, ones, suma);
    __builtin_amdgcn_s_setprio(1);
#pragma unroll
    for (int nt = 0; nt < 8; nt++) {
      const int vrr = nt * 16 + l16;
      const int vsw = (quad ^ ((vrr >> 3) & 3)) * 8;   // match staging swizzle
      bf16x8 vbh = *(const bf16x8*)&vtb[cur][0][vrr][vsw];
      bf16x8 vbl = *(const bf16x8*)&vtb[cur][1][vrr][vsw];
      f32x4 c = oacc[nt];
      c = mfma16(ph, vbh, c);
      c = mfma16(ph, vbl, c);
      c = mfma16(plv, vbh, c);
      oacc[nt] = c;
    }
    __builtin_amdgcn_s_setprio(0);
  }

  // ---- epilogue: O / sum ----------------------------------------------------
  f32x4 inv;
#pragma unroll
  for (int rg = 0; rg < 4; rg++) inv[rg] = 1.0f / suma[rg];
#pragma unroll
  for (int nt = 0; nt < 8; nt++)
#pragma unroll
    for (int rg = 0; rg < 4; rg++) {
      const size_t row = qrow0 + w * 16 + quad * 4 + rg;
      O[row * CC + h * CD + nt * 16 + l16] = oacc[nt][rg] * inv[rg];
    }
}

// ---------------------------------------------------------------------------
extern "C" void kernel_launch(void* const* d_in, const int* in_sizes, int n_in,
                              void* d_out, int out_size, void* d_ws, size_t ws_size,
                              hipStream_t stream)
{
  (void)in_sizes; (void)n_in; (void)out_size; (void)ws_size;
  const float* x    = (const float*)d_in[0];
  const float* cond = (const float*)d_in[1];
  const float* mask = (const float*)d_in[2];
  const float* wq   = (const float*)d_in[3];
  const float* bq   = (const float*)d_in[4];
  const float* wk   = (const float*)d_in[5];
  const float* bk   = (const float*)d_in[6];
  const float* wv   = (const float*)d_in[7];
  const float* bv   = (const float*)d_in[8];
  const float* wo   = (const float*)d_in[9];
  const float* bo   = (const float*)d_in[10];
  float* out = (float*)d_out;

  char* wsb = (char*)d_ws;
  size_t off = 0;
  auto alloc = [&](size_t bytes) -> char* {
    char* p = wsb + off;
    off += (bytes + 255) & ~(size_t)255;
    return p;
  };
  // Region 1 (dead before attention; Obuf 64 MiB aliases qx..Kf)
  signed char* qx  = (signed char*)alloc((size_t)TOK * CC);  // 16 MiB
  signed char* qwq = (signed char*)alloc((size_t)CC * CC);   //  4 MiB
  bf16* ch  = (bf16*)alloc((size_t)LR * CC * 2);   //  4 MiB
  bf16* cl_ = (bf16*)alloc((size_t)LR * CC * 2);   //  4 MiB
  bf16* wkh = (bf16*)alloc((size_t)CC * CC * 2);   //  8 MiB
  bf16* wkl = (bf16*)alloc((size_t)CC * CC * 2);   //  8 MiB
  bf16* wvh = (bf16*)alloc((size_t)CC * CC * 2);   //  8 MiB
  bf16* wvl = (bf16*)alloc((size_t)CC * CC * 2);   //  8 MiB
  float* Kf = (float*)alloc((size_t)LR * CC * 4);  //  8 MiB (split-K accum)
  float* Vf = (float*)alloc((size_t)LR * CC * 4);  //  8 MiB (contiguous after Kf)
  float* Obuf = (float*)qx;                        // alias: 64 MiB over qx..Kf
  // Region 2 (live through attention)
  bf16* qhb = (bf16*)alloc((size_t)TOK * CC * 2);  // 32 MiB (later reused as qO)
  bf16* qlb = (bf16*)alloc((size_t)TOK * CC * 2);  // 32 MiB
  bf16* khb = (bf16*)alloc((size_t)LR * CC * 2);
  bf16* klb = (bf16*)alloc((size_t)LR * CC * 2);
  bf16* vth = (bf16*)alloc((size_t)LR * CC * 2);   // V^T [b,h,d,l] hi
  bf16* vtl = (bf16*)alloc((size_t)LR * CC * 2);   // V^T [b,h,d,l] lo
  signed char* qwo = (signed char*)alloc((size_t)CC * CC);
  float* sx  = (float*)alloc((size_t)TOK * 4);
  float* swq = (float*)alloc((size_t)CC * 4);
  float* swo = (float*)alloc((size_t)CC * 4);
  float* sO  = (float*)alloc((size_t)TOK * 4);
  signed char* qO = (signed char*)qhb;   // alias: qh/ql dead after attention

  // 1) quantize weights and x (int8, swizzled for gemm_i8)
  quant_rows_i8<<<CC,  256, 0, stream>>>(wq, qwq, swq);
  quant_rows_i8<<<CC,  256, 0, stream>>>(wo, qwo, swo);
  quant_rows_i8<<<TOK, 256, 0, stream>>>(x, qx, sx);
  // 2) split fp32 inputs for the fp32-emulated GEMMs
  split_pair_k<<<(LR * CC / 4) / 256, 256, 0, stream>>>(cond, ch, cl_);
  split_pair_k<<<(CC * CC / 4) / 256, 256, 0, stream>>>(wk, wkh, wkl);
  split_pair_k<<<(CC * CC / 4) / 256, 256, 0, stream>>>(wv, wvh, wvl);
  // 3) Q = dequant(qx @ qwq^T) + bq, written as bf16 hi/lo split  (i8 MFMA)
  gemm_i8<1><<<dim3(CC / 128, TOK / 128, 1), 256, 0, stream>>>(
      qx, qwq, nullptr, qhb, qlb, sx, swq, bq, CC, CC);
  // 4) K/V projections: fused-KV + split-K x4 (atomic fp32 accum)
  (void)hipMemsetAsync(Kf, 0, (size_t)LR * CC * 4 * 2, stream);  // Kf+Vf contiguous
  gemm_kv<<<dim3(CC / 128, LR / 128, 8), 256, 0, stream>>>(
      ch, cl_, wkh, wkl, wvh, wvl, Kf, Vf, CC, CC, 512);
  bias_split_k<<<(LR * CC / 4) / 256, 256, 0, stream>>>(Kf, bk, khb, klb);
  bias_split_vt_k<<<dim3(CL / 32, CD / 32, CB * CH), 256, 0, stream>>>(Vf, bv, vth, vtl);
  // 5) attention: 256-row Q tiles, 1024 threads, 1-barrier dbuf pipeline
  attn_k<<<dim3(CN / 256, CH, CB), 1024, 0, stream>>>(
      qhb, qlb, khb, klb, vth, vtl, mask, Obuf);
  // 6) requant O (int8 swizzled), then output projection (i8 MFMA)
  quant_rows_i8<<<TOK, 256, 0, stream>>>(Obuf, qO, sO);
  gemm_i8<0><<<dim3(CC / 128, TOK / 128, 1), 256, 0, stream>>>(
      qO, qwo, out, nullptr, nullptr, sO, swo, bo, CC, CC);
}

// Round 4
// 500.455 us; speedup vs baseline: 1.1069x; 1.1069x over previous
//
#include <hip/hip_runtime.h>
#include <cstdint>
#include <cstddef>

// ---------------------------------------------------------------------------
// QuantCrossAttention, MI355X/gfx950.  B=2 N=4096 L=512 C=2048 H=16 D=128.
// - int8 quant replicated bit-exactly (IEEE div, rintf=RNE, max-chain)
// - w8a8 GEMMs on TRUE i8 MFMA (mfma_i32_16x16x64_i8), operands XOR-swizzled
//   in GLOBAL layout so global_load_lds stages verbatim.
// - fp32 GEMMs (K/V proj, QK^T, PV) via bf16 hi/lo split, 3 MFMA terms
// R6: T14 issue-early/write-late staging in attn; 2-phase dbuf in gemm_i8.
// R7: attn reg diet (2 blocks/CU) + T1 XCD swizzle everywhere.
// R8: attn 1024-thr / 16-wave / dbuf ks+vt / ONE barrier per chunk (121 us).
// R9 (theory: non-attn is 433 us = 78%; the K/V projection path burns 4
//     dispatches + ~130 MB intermediate traffic: memset -> split-K=4 atomic
//     gemm_kv -> bias_split_k -> bias_split_vt):
//   * gemm_kv2: single-K (sequential, deterministic — replaces random-order
//     atomics), 2-phase dbuf staging (R6-verified pattern), fused epilogue:
//     bias + hi/lo split + (V) LDS-transpose -> writes khb/klb/vth/vtl
//     directly.  Eliminates memset, Kf/Vf, both bias_split kernels, all
//     atomic traffic.  Grid (16,8,2)=256, bijective XCD swizzle.
// ---------------------------------------------------------------------------

typedef __bf16 bf16;
typedef __bf16 bf16x8 __attribute__((ext_vector_type(8)));
typedef __bf16 bf16x4 __attribute__((ext_vector_type(4)));
typedef float  f32x4  __attribute__((ext_vector_type(4)));
typedef int    i32x4  __attribute__((ext_vector_type(4)));

#define DEV __device__ __forceinline__

static constexpr int CB = 2;
static constexpr int CN = 4096;
static constexpr int CL = 512;
static constexpr int CC = 2048;
static constexpr int CH = 16;
static constexpr int CD = 128;
static constexpr int TOK = CB * CN;  // 8192 tokens
static constexpr int LR  = CB * CL;  // 1024 cond rows

DEV void gl_lds16(const void* g, void* l) {
  __builtin_amdgcn_global_load_lds(
      (const __attribute__((address_space(1))) unsigned int*)g,
      (__attribute__((address_space(3))) unsigned int*)l, 16, 0, 0);
}

DEV f32x4 mfma16(bf16x8 a, bf16x8 b, f32x4 c) {
  return __builtin_amdgcn_mfma_f32_16x16x32_bf16(a, b, c, 0, 0, 0);
}

DEV i32x4 mfma_i8(i32x4 a, i32x4 b, i32x4 c) {
  return __builtin_amdgcn_mfma_i32_16x16x64_i8(a, b, c, 0, 0, 0);
}

// --------- per-row symmetric int8 quant -> swizzled int8 + scale ------------
__global__ __launch_bounds__(256) void quant_rows_i8(
    const float* __restrict__ in, signed char* __restrict__ q,
    float* __restrict__ scale)
{
  const int r = blockIdx.x, t = threadIdx.x;
  const float* x = in + (size_t)r * CC;
  const float4 v0 = ((const float4*)x)[2 * t];
  const float4 v1 = ((const float4*)x)[2 * t + 1];
  float m = fmaxf(fmaxf(fmaxf(fabsf(v0.x), fabsf(v0.y)), fmaxf(fabsf(v0.z), fabsf(v0.w))),
                  fmaxf(fmaxf(fabsf(v1.x), fabsf(v1.y)), fmaxf(fabsf(v1.z), fabsf(v1.w))));
#pragma unroll
  for (int off = 32; off > 0; off >>= 1) m = fmaxf(m, __shfl_xor(m, off));
  __shared__ float sm[4];
  if ((t & 63) == 0) sm[t >> 6] = m;
  __syncthreads();
  m = fmaxf(fmaxf(sm[0], sm[1]), fmaxf(sm[2], sm[3]));
  const float s = fmaxf(m / 127.0f, 1e-8f);   // IEEE divide: bit-matches np
  if (t == 0) scale[r] = s;
  const float a[8] = {v0.x, v0.y, v0.z, v0.w, v1.x, v1.y, v1.z, v1.w};
  int2 pk;
  int lo = 0, hi = 0;
#pragma unroll
  for (int j = 0; j < 4; j++) {
    const int b0 = (int)fminf(fmaxf(rintf(a[j]     / s), -127.f), 127.f);
    const int b1 = (int)fminf(fmaxf(rintf(a[4 + j] / s), -127.f), 127.f);
    lo |= (b0 & 255) << (8 * j);
    hi |= (b1 & 255) << (8 * j);
  }
  pk.x = lo; pk.y = hi;
  const int c0 = t * 8;
  const int f = (r >> 1) & 3;
  const int pos = (c0 & ~63) | ((((c0 >> 4) & 3) ^ f) << 4) | (c0 & 15);
  *(int2*)&q[(size_t)r * CC + pos] = pk;
}

// --------- fp32 -> bf16 hi/lo split ----------------------------------------
__global__ __launch_bounds__(256) void split_pair_k(
    const float* __restrict__ in, bf16* __restrict__ hi, bf16* __restrict__ lo)
{
  const size_t i = (size_t)blockIdx.x * 256 + threadIdx.x;  // float4 index
  const float4 v = ((const float4*)in)[i];
  const float a[4] = {v.x, v.y, v.z, v.w};
  bf16x4 h4, l4;
#pragma unroll
  for (int j = 0; j < 4; j++) {
    bf16 h = (bf16)a[j];
    h4[j] = h;
    l4[j] = (bf16)(a[j] - (float)h);
  }
  ((bf16x4*)hi)[i] = h4;
  ((bf16x4*)lo)[i] = l4;
}

// --------- int8 GEMM, A[M,K] * B[Nd,K]^T, both K-major, pre-swizzled --------
// 2-phase double-buffered pipeline (one barrier per K-step) + T1 XCD swizzle.
template <int MODE>
__global__ __launch_bounds__(256) void gemm_i8(
    const signed char* __restrict__ A, const signed char* __restrict__ B,
    float* __restrict__ out0, bf16* __restrict__ outH, bf16* __restrict__ outL,
    const float* __restrict__ rowS, const float* __restrict__ colS,
    const float* __restrict__ bias, const int Nd, const int K)
{
  __shared__ signed char sA[2][128 * 64] __attribute__((aligned(16)));
  __shared__ signed char sB[2][128 * 64] __attribute__((aligned(16)));
  const int t = threadIdx.x;
  int lin = blockIdx.y * 16 + blockIdx.x;          // grid = (16, 64) = 1024
  lin = (lin & 7) * 128 + (lin >> 3);              // XCD-contiguous logical id
  const int m0 = (lin >> 4) * 128, n0 = (lin & 15) * 128;
  const int srow = t >> 2, scol = (t & 3) * 16;   // 64 rows/instr, 16B/lane
  const signed char* aP = A + (size_t)(m0 + srow) * K + scol;
  const signed char* bP = B + (size_t)(n0 + srow) * K + scol;
  const int lane = t & 63, wave = t >> 6;
  const int wm = (wave >> 1) * 64, wn = (wave & 1) * 64;
  const int quad = lane >> 4, l16 = lane & 15;
  i32x4 acc[4][4] = {};

  // prologue: stage k-block 0 into buffer 0
  gl_lds16(aP,                  &sA[0][t * 16]);
  gl_lds16(aP + (size_t)64 * K, &sA[0][4096 + t * 16]);
  gl_lds16(bP,                  &sB[0][t * 16]);
  gl_lds16(bP + (size_t)64 * K, &sB[0][4096 + t * 16]);
  __syncthreads();

  int cur = 0;
  for (int kb = 0; kb < K; kb += 64) {
    const int nx = kb + 64;
    if (nx < K) {   // stage next k-block into the other buffer (async)
      gl_lds16(aP + nx,                  &sA[cur ^ 1][t * 16]);
      gl_lds16(aP + nx + (size_t)64 * K, &sA[cur ^ 1][4096 + t * 16]);
      gl_lds16(bP + nx,                  &sB[cur ^ 1][t * 16]);
      gl_lds16(bP + nx + (size_t)64 * K, &sB[cur ^ 1][4096 + t * 16]);
    }
    i32x4 fa[4], fb[4];
#pragma unroll
    for (int i = 0; i < 4; i++) {
      const int ra = wm + i * 16 + l16;
      const int rb = wn + i * 16 + l16;
      fa[i] = *(const i32x4*)&sA[cur][ra * 64 + (quad ^ ((ra >> 1) & 3)) * 16];
      fb[i] = *(const i32x4*)&sB[cur][rb * 64 + (quad ^ ((rb >> 1) & 3)) * 16];
    }
#pragma unroll
    for (int mt = 0; mt < 4; mt++)
#pragma unroll
      for (int nt = 0; nt < 4; nt++)
        acc[mt][nt] = mfma_i8(fa[mt], fb[nt], acc[mt][nt]);
    __syncthreads();   // drains vmcnt(0): buf^1 staged; lgkm: buf reads done
    cur ^= 1;
  }

  // epilogue: C/D layout col=lane&15, row=quad*4+reg (shape-determined)
#pragma unroll
  for (int mt = 0; mt < 4; mt++)
#pragma unroll
    for (int nt = 0; nt < 4; nt++)
#pragma unroll
      for (int rg = 0; rg < 4; rg++) {
        const int mr = m0 + wm + mt * 16 + quad * 4 + rg;
        const int nc = n0 + wn + nt * 16 + l16;
        const float a = (float)acc[mt][nt][rg];
        const float sc = rowS[mr] * colS[nc];   // (sx*sw) first: matches np
        const float v = a * sc + bias[nc];
        if (MODE == 0) {
          out0[(size_t)mr * Nd + nc] = v;
        } else {
          const bf16 h = (bf16)v;
          outH[(size_t)mr * Nd + nc] = h;
          outL[(size_t)mr * Nd + nc] = (bf16)(v - (float)h);
        }
      }
}

// --------- bf16-split GEMM for K/V projections, fully fused -----------------
// R9: single-K (sequential, 64 steps of 32), 2-phase dbuf staging, epilogue
// fuses bias + hi/lo split; V path additionally transposes [l,d]->[d,l] via
// a padded LDS tile.  No atomics, no split-K, no intermediate Kf/Vf.
// Grid (16 n, 8 m, 2 kv) = 256 blocks, bijective XCD swizzle.
__global__ __launch_bounds__(256) void gemm_kv2(
    const bf16* __restrict__ Ah, const bf16* __restrict__ Al,
    const bf16* __restrict__ B0h, const bf16* __restrict__ B0l,
    const bf16* __restrict__ B1h, const bf16* __restrict__ B1l,
    bf16* __restrict__ outKh, bf16* __restrict__ outKl,
    bf16* __restrict__ outVh, bf16* __restrict__ outVl,
    const float* __restrict__ bk, const float* __restrict__ bv)
{
  // arena: staging 4 arrays x [2][128*32] bf16 (16 KiB each) = 64 KiB;
  // epilogue V-transpose tile [128][129] fp32 = 66048 B aliases it.
  __shared__ char arena[128 * 129 * 4] __attribute__((aligned(16)));
  bf16 (*sAh)[128 * 32] = (bf16 (*)[128 * 32])(arena);
  bf16 (*sBh)[128 * 32] = (bf16 (*)[128 * 32])(arena + 16384);
  bf16 (*sAl)[128 * 32] = (bf16 (*)[128 * 32])(arena + 32768);
  bf16 (*sBl)[128 * 32] = (bf16 (*)[128 * 32])(arena + 49152);
  const int t = threadIdx.x;
  const int K = CC;
  int lin = (blockIdx.z * 8 + blockIdx.y) * 16 + blockIdx.x;  // 256 blocks
  lin = (lin & 7) * 32 + (lin >> 3);                          // XCD swizzle
  const int n0 = (lin & 15) * 128;
  const int m0 = ((lin >> 4) & 7) * 128;
  const int kv = lin >> 7;
  const bf16* Bh = kv ? B1h : B0h;
  const bf16* Bl = kv ? B1l : B0l;
  const int srow = t >> 2, scol = (t & 3) * 8;
  const bf16* aP  = Ah + (size_t)(m0 + srow) * K + scol;
  const bf16* bP  = Bh + (size_t)(n0 + srow) * K + scol;
  const bf16* aPl = Al + (size_t)(m0 + srow) * K + scol;
  const bf16* bPl = Bl + (size_t)(n0 + srow) * K + scol;
  const int lane = t & 63, wave = t >> 6;
  const int wm = (wave >> 1) * 64, wn = (wave & 1) * 64;
  const int quad = lane >> 4, l16 = lane & 15;
  f32x4 acc[4][4] = {};

  // prologue: stage k-block 0 into buffer 0
  gl_lds16(aP,                  &sAh[0][t * 8]);
  gl_lds16(aP + (size_t)64 * K, &sAh[0][2048 + t * 8]);
  gl_lds16(bP,                  &sBh[0][t * 8]);
  gl_lds16(bP + (size_t)64 * K, &sBh[0][2048 + t * 8]);
  gl_lds16(aPl,                  &sAl[0][t * 8]);
  gl_lds16(aPl + (size_t)64 * K, &sAl[0][2048 + t * 8]);
  gl_lds16(bPl,                  &sBl[0][t * 8]);
  gl_lds16(bPl + (size_t)64 * K, &sBl[0][2048 + t * 8]);
  __syncthreads();

  int cur = 0;
  for (int kb = 0; kb < K; kb += 32) {
    const int nx = kb + 32;
    if (nx < K) {   // stage next k-block into the other buffer (async)
      gl_lds16(aP + nx,                  &sAh[cur ^ 1][t * 8]);
      gl_lds16(aP + nx + (size_t)64 * K, &sAh[cur ^ 1][2048 + t * 8]);
      gl_lds16(bP + nx,                  &sBh[cur ^ 1][t * 8]);
      gl_lds16(bP + nx + (size_t)64 * K, &sBh[cur ^ 1][2048 + t * 8]);
      gl_lds16(aPl + nx,                  &sAl[cur ^ 1][t * 8]);
      gl_lds16(aPl + nx + (size_t)64 * K, &sAl[cur ^ 1][2048 + t * 8]);
      gl_lds16(bPl + nx,                  &sBl[cur ^ 1][t * 8]);
      gl_lds16(bPl + nx + (size_t)64 * K, &sBl[cur ^ 1][2048 + t * 8]);
    }
    bf16x8 fa[4], fb[4], fal[4], fbl[4];
#pragma unroll
    for (int i = 0; i < 4; i++) {
      fa[i]  = *(const bf16x8*)&sAh[cur][(wm + i * 16 + l16) * 32 + quad * 8];
      fb[i]  = *(const bf16x8*)&sBh[cur][(wn + i * 16 + l16) * 32 + quad * 8];
      fal[i] = *(const bf16x8*)&sAl[cur][(wm + i * 16 + l16) * 32 + quad * 8];
      fbl[i] = *(const bf16x8*)&sBl[cur][(wn + i * 16 + l16) * 32 + quad * 8];
    }
#pragma unroll
    for (int mt = 0; mt < 4; mt++)
#pragma unroll
      for (int nt = 0; nt < 4; nt++) {
        f32x4 c = acc[mt][nt];
        c = mfma16(fa[mt],  fb[nt],  c);
        c = mfma16(fa[mt],  fbl[nt], c);
        c = mfma16(fal[mt], fb[nt],  c);
        acc[mt][nt] = c;
      }
    __syncthreads();   // buf^1 staged (vmcnt drained); buf reads done
    cur ^= 1;
  }

  if (kv == 0) {
    // ---- K path: bias + hi/lo split, direct store ----
#pragma unroll
    for (int mt = 0; mt < 4; mt++)
#pragma unroll
      for (int nt = 0; nt < 4; nt++)
#pragma unroll
        for (int rg = 0; rg < 4; rg++) {
          const int mr = m0 + wm + mt * 16 + quad * 4 + rg;
          const int nc = n0 + wn + nt * 16 + l16;
          const float v = acc[mt][nt][rg] + bk[nc];
          const bf16 h = (bf16)v;
          outKh[(size_t)mr * CC + nc] = h;
          outKl[(size_t)mr * CC + nc] = (bf16)(v - (float)h);
        }
  } else {
    // ---- V path: bias -> LDS tile -> transpose -> hi/lo split ----
    float (*tile)[129] = (float (*)[129])arena;   // aliases staging (done)
#pragma unroll
    for (int mt = 0; mt < 4; mt++)
#pragma unroll
      for (int nt = 0; nt < 4; nt++)
#pragma unroll
        for (int rg = 0; rg < 4; rg++) {
          const int lm = wm + mt * 16 + quad * 4 + rg;
          const int ln = wn + nt * 16 + l16;
          tile[lm][ln] = acc[mt][nt][rg] + bv[n0 + ln];
        }
    __syncthreads();
    // n0 spans exactly one head (BN = CD = 128); m0 spans one b (128 | 512)
    const int h = n0 >> 7, b = m0 >> 9, lbase = m0 & (CL - 1);
    const int d = t & 127, half = t >> 7;      // 256 thr: 128 d x 2 l-halves
    const size_t orow = ((size_t)(b * CH + h) * CD + d) * CL + lbase + half * 64;
#pragma unroll
    for (int jv = 0; jv < 8; jv++) {
      bf16x8 h8, l8;
#pragma unroll
      for (int j = 0; j < 8; j++) {
        const float v = tile[half * 64 + jv * 8 + j][d];
        const bf16 hh = (bf16)v;
        h8[j] = hh;
        l8[j] = (bf16)(v - (float)hh);
      }
      *(bf16x8*)&outVh[orow + jv * 8] = h8;
      *(bf16x8*)&outVl[orow + jv * 8] = l8;
    }
  }
}

// --------- flash attention, split-bf16, MAX-FREE softmax --------------------
// R8: 1024 thr / 16 waves / 256 Q rows; ONE block per CU.  ks+vt both
// double-buffered; prefetch distance 2; ONE barrier per chunk.
__global__ __launch_bounds__(1024, 4) void attn_k(
    const bf16* __restrict__ qh, const bf16* __restrict__ ql,
    const bf16* __restrict__ kh, const bf16* __restrict__ kl,
    const bf16* __restrict__ vth, const bf16* __restrict__ vtl,
    const float* __restrict__ mask, float* __restrict__ O)
{
  // arena: ks [2][2][32][136] (34816 B) | vt [2][2][128][32] (32768 B)
  //        | ps [16][16][36] (36864 B)  = 104448 B
  __shared__ char arena[34816 + 32768 + 36864] __attribute__((aligned(16)));
  bf16 (*ksb)[2][32][136] = (bf16 (*)[2][32][136])arena;           // [dbuf][hilo]
  bf16 (*vtb)[2][128][32] = (bf16 (*)[2][128][32])(arena + 34816); // [dbuf][hilo]
  float (*ps)[16][36] = (float (*)[16][36])(arena + 34816 + 32768);
  const int t = threadIdx.x, lane = t & 63, w = t >> 6;   // w in 0..15
  const int quad = lane >> 4, l16 = lane & 15;
  int lin = (blockIdx.z * 16 + blockIdx.y) * 16 + blockIdx.x;  // (16,16,2)=512
  lin = (lin & 7) * 64 + (lin >> 3);                           // XCD swizzle
  const int n0 = (lin & 15) * 256;
  const int h  = (lin >> 4) & 15;
  const int b  = lin >> 8;
  const int bh = b * CH + h;
  const size_t qrow0 = (size_t)b * CN + n0;
  const float* mrow_base = mask + ((size_t)b * CN + n0 + w * 16 + quad * 4) * CL;

  // ---- staging-lane geometry (1024 thr: plane = hi/lo by t>>9) ----
  const int pl   = t >> 9;                       // 0 = hi, 1 = lo
  const int krow = (t >> 4) & 31, ksg = t & 15;  // K: 32 l-rows x 128 d, 16B
  const int vrow = (t >> 2) & 127, vsg = t & 3;  // V^T: 128 d-rows x 32 l, 16B
  const bf16* kPsrc = pl ? kl : kh;
  const bf16* vPsrc = pl ? vtl : vth;
  const int vc = (vsg ^ ((vrow >> 3) & 3)) * 8;  // XOR chunk swizzle (fixed)
  uint4 kr, vr;
  // chunk-0 prefetch (overlaps Q preamble)
  kr = *(const uint4*)(kPsrc + ((size_t)b * CL + krow) * CC + h * CD + ksg * 8);
  vr = *(const uint4*)(vPsrc + ((size_t)bh * CD + vrow) * CL + vsg * 8);

  // ---- Q fragments into registers (staged via arena for coalescing) ----
  bf16x8 qfh[4], qfl[4];
  {
    bf16* qs = (bf16*)arena;   // 256 rows x 136 = 69632 B (ps not yet live)
    const int row = t >> 2, sg = t & 3;
    {
      const bf16* src = qh + (qrow0 + row) * CC + h * CD + sg * 32;
      bf16* dst = qs + row * 136 + sg * 32;
#pragma unroll
      for (int j = 0; j < 4; j++) ((uint4*)dst)[j] = ((const uint4*)src)[j];
    }
    __syncthreads();
#pragma unroll
    for (int s = 0; s < 4; s++)
      qfh[s] = *(const bf16x8*)&qs[(w * 16 + l16) * 136 + s * 32 + quad * 8];
    __syncthreads();
    {
      const bf16* src = ql + (qrow0 + row) * CC + h * CD + sg * 32;
      bf16* dst = qs + row * 136 + sg * 32;
#pragma unroll
      for (int j = 0; j < 4; j++) ((uint4*)dst)[j] = ((const uint4*)src)[j];
    }
    __syncthreads();
#pragma unroll
    for (int s = 0; s < 4; s++)
      qfl[s] = *(const bf16x8*)&qs[(w * 16 + l16) * 136 + s * 32 + quad * 8];
    __syncthreads();   // qs reads done; arena now owned by ks/vt/ps
  }

  // ---- pipeline prologue: write chunk0 -> buf0; load chunk1 regs ----
  *(uint4*)&ksb[0][pl][krow][ksg * 8] = kr;
  *(uint4*)&vtb[0][pl][vrow][vc] = vr;
  kr = *(const uint4*)(kPsrc + ((size_t)b * CL + 32 + krow) * CC + h * CD + ksg * 8);
  vr = *(const uint4*)(vPsrc + ((size_t)bh * CD + vrow) * CL + 32 + vsg * 8);

  f32x4 oacc[8] = {};
  f32x4 suma = {};          // row-sum accumulator (MFMA ones-trick)
  const bf16 one = (bf16)1.0f;
  const bf16x8 ones = {one, one, one, one, one, one, one, one};
  const float isd = 0.08838834764831845f;   // np.float32(1/sqrt(128))

  for (int ci = 0; ci < CL / 32; ci++) {
    const int cur = ci & 1;
    __syncthreads();   // closes chunk ci-1 reads of buf^1; buf[cur] visible
    // ---- write-late: chunk ci+1 regs -> other buffer (overlaps compute) --
    if (ci + 1 < CL / 32) {
      *(uint4*)&ksb[cur ^ 1][pl][krow][ksg * 8] = kr;
      *(uint4*)&vtb[cur ^ 1][pl][vrow][vc] = vr;
    }
    // ---- issue-early: chunk ci+2 prefetch (full chunk of latency cover) --
    if (ci + 2 < CL / 32) {
      const int lcn = (ci + 2) * 32;
      kr = *(const uint4*)(kPsrc + ((size_t)b * CL + lcn + krow) * CC + h * CD + ksg * 8);
      vr = *(const uint4*)(vPsrc + ((size_t)bh * CD + vrow) * CL + lcn + vsg * 8);
    }
    // ---- current-chunk mask loads (QK covers the latency) ----------------
    const int lc = ci * 32;
    float mcur[2][4];
#pragma unroll
    for (int rg = 0; rg < 4; rg++) {
      const float* mrp = mrow_base + (size_t)rg * CL + lc;
      mcur[0][rg] = mrp[l16];
      mcur[1][rg] = mrp[16 + l16];
    }

    // ---- S = Q K^T (split, 3 terms), two 16x16 l-tiles -------------------
    f32x4 sacc[2] = {};
    __builtin_amdgcn_s_setprio(1);
#pragma unroll
    for (int s = 0; s < 4; s++) {
#pragma unroll
      for (int lt = 0; lt < 2; lt++) {
        bf16x8 kbh = *(const bf16x8*)&ksb[cur][0][lt * 16 + l16][s * 32 + quad * 8];
        bf16x8 kbl = *(const bf16x8*)&ksb[cur][1][lt * 16 + l16][s * 32 + quad * 8];
        sacc[lt] = mfma16(qfh[s], kbh, sacc[lt]);
        sacc[lt] = mfma16(qfh[s], kbl, sacc[lt]);
        sacc[lt] = mfma16(qfl[s], kbh, sacc[lt]);
      }
    }
    __builtin_amdgcn_s_setprio(0);

    // ---- MAX-FREE softmax: u = exp(s*isd + mask); sum rides MFMA ---------
    float u[2][4];
#pragma unroll
    for (int rg = 0; rg < 4; rg++) {
      u[0][rg] = __expf(sacc[0][rg] * isd + mcur[0][rg]);
      u[1][rg] = __expf(sacc[1][rg] * isd + mcur[1][rg]);
    }

    // ---- P: C-layout -> A-layout via wave-private LDS round-trip ---------
#pragma unroll
    for (int lt = 0; lt < 2; lt++)
#pragma unroll
      for (int rg = 0; rg < 4; rg++)
        ps[w][quad * 4 + rg][lt * 16 + l16] = u[lt][rg];
    const float4 p0 = *(const float4*)&ps[w][l16][quad * 8];
    const float4 p1 = *(const float4*)&ps[w][l16][quad * 8 + 4];
    const float pv[8] = {p0.x, p0.y, p0.z, p0.w, p1.x, p1.y, p1.z, p1.w};
    bf16x8 ph, plv;
#pragma unroll
    for (int j = 0; j < 8; j++) {
      bf16 hh = (bf16)pv[j];
      ph[j] = hh;
      plv[j] = (bf16)(pv[j] - (float)hh);
    }

    // ---- O += P V (split, 3 terms) + row-sum channel ---------------------
    suma = mfma16(ph, ones, suma);
    suma = mfma16(plv, ones, suma);
    __builtin_amdgcn_s_setprio(1);
#pragma unroll
    for (int nt = 0; nt < 8; nt++) {
      const int vrr = nt * 16 + l16;
      const int vsw = (quad ^ ((vrr >> 3) & 3)) * 8;   // match staging swizzle
      bf16x8 vbh = *(const bf16x8*)&vtb[cur][0][vrr][vsw];
      bf16x8 vbl = *(const bf16x8*)&vtb[cur][1][vrr][vsw];
      f32x4 c = oacc[nt];
      c = mfma16(ph, vbh, c);
      c = mfma16(ph, vbl, c);
      c = mfma16(plv, vbh, c);
      oacc[nt] = c;
    }
    __builtin_amdgcn_s_setprio(0);
  }

  // ---- epilogue: O / sum ----------------------------------------------------
  f32x4 inv;
#pragma unroll
  for (int rg = 0; rg < 4; rg++) inv[rg] = 1.0f / suma[rg];
#pragma unroll
  for (int nt = 0; nt < 8; nt++)
#pragma unroll
    for (int rg = 0; rg < 4; rg++) {
      const size_t row = qrow0 + w * 16 + quad * 4 + rg;
      O[row * CC + h * CD + nt * 16 + l16] = oacc[nt][rg] * inv[rg];
    }
}

// ---------------------------------------------------------------------------
extern "C" void kernel_launch(void* const* d_in, const int* in_sizes, int n_in,
                              void* d_out, int out_size, void* d_ws, size_t ws_size,
                              hipStream_t stream)
{
  (void)in_sizes; (void)n_in; (void)out_size; (void)ws_size;
  const float* x    = (const float*)d_in[0];
  const float* cond = (const float*)d_in[1];
  const float* mask = (const float*)d_in[2];
  const float* wq   = (const float*)d_in[3];
  const float* bq   = (const float*)d_in[4];
  const float* wk   = (const float*)d_in[5];
  const float* bk   = (const float*)d_in[6];
  const float* wv   = (const float*)d_in[7];
  const float* bv   = (const float*)d_in[8];
  const float* wo   = (const float*)d_in[9];
  const float* bo   = (const float*)d_in[10];
  float* out = (float*)d_out;

  char* wsb = (char*)d_ws;
  size_t off = 0;
  auto alloc = [&](size_t bytes) -> char* {
    char* p = wsb + off;
    off += (bytes + 255) & ~(size_t)255;
    return p;
  };
  // Region 1 (dead before attention; Obuf 64 MiB aliases qx..wvl)
  signed char* qx  = (signed char*)alloc((size_t)TOK * CC);  // 16 MiB
  signed char* qwq = (signed char*)alloc((size_t)CC * CC);   //  4 MiB
  bf16* ch  = (bf16*)alloc((size_t)LR * CC * 2);   //  4 MiB
  bf16* cl_ = (bf16*)alloc((size_t)LR * CC * 2);   //  4 MiB
  bf16* wkh = (bf16*)alloc((size_t)CC * CC * 2);   //  8 MiB
  bf16* wkl = (bf16*)alloc((size_t)CC * CC * 2);   //  8 MiB
  bf16* wvh = (bf16*)alloc((size_t)CC * CC * 2);   //  8 MiB
  bf16* wvl = (bf16*)alloc((size_t)CC * CC * 2);   //  8 MiB
  (void)alloc((size_t)16 << 20);                   // 16 MiB spacer (Obuf tail)
  float* Obuf = (float*)qx;                        // alias: 64 MiB over qx..spacer
  // Region 2 (live through attention)
  bf16* qhb = (bf16*)alloc((size_t)TOK * CC * 2);  // 32 MiB (later reused as qO)
  bf16* qlb = (bf16*)alloc((size_t)TOK * CC * 2);  // 32 MiB
  bf16* khb = (bf16*)alloc((size_t)LR * CC * 2);
  bf16* klb = (bf16*)alloc((size_t)LR * CC * 2);
  bf16* vth = (bf16*)alloc((size_t)LR * CC * 2);   // V^T [b,h,d,l] hi
  bf16* vtl = (bf16*)alloc((size_t)LR * CC * 2);   // V^T [b,h,d,l] lo
  signed char* qwo = (signed char*)alloc((size_t)CC * CC);
  float* sx  = (float*)alloc((size_t)TOK * 4);
  float* swq = (float*)alloc((size_t)CC * 4);
  float* swo = (float*)alloc((size_t)CC * 4);
  float* sO  = (float*)alloc((size_t)TOK * 4);
  signed char* qO = (signed char*)qhb;   // alias: qh/ql dead after attention

  // 1) quantize weights and x (int8, swizzled for gemm_i8)
  quant_rows_i8<<<CC,  256, 0, stream>>>(wq, qwq, swq);
  quant_rows_i8<<<CC,  256, 0, stream>>>(wo, qwo, swo);
  quant_rows_i8<<<TOK, 256, 0, stream>>>(x, qx, sx);
  // 2) split fp32 inputs for the fp32-emulated GEMMs
  split_pair_k<<<(LR * CC / 4) / 256, 256, 0, stream>>>(cond, ch, cl_);
  split_pair_k<<<(CC * CC / 4) / 256, 256, 0, stream>>>(wk, wkh, wkl);
  split_pair_k<<<(CC * CC / 4) / 256, 256, 0, stream>>>(wv, wvh, wvl);
  // 3) Q = dequant(qx @ qwq^T) + bq, written as bf16 hi/lo split  (i8 MFMA)
  gemm_i8<1><<<dim3(CC / 128, TOK / 128, 1), 256, 0, stream>>>(
      qx, qwq, nullptr, qhb, qlb, sx, swq, bq, CC, CC);
  // 4) K/V projections: single-K dbuf GEMM, fused bias+split(+V transpose)
  gemm_kv2<<<dim3(CC / 128, LR / 128, 2), 256, 0, stream>>>(
      ch, cl_, wkh, wkl, wvh, wvl, khb, klb, vth, vtl, bk, bv);
  // 5) attention: 256-row Q tiles, 1024 threads, 1-barrier dbuf pipeline
  attn_k<<<dim3(CN / 256, CH, CB), 1024, 0, stream>>>(
      qhb, qlb, khb, klb, vth, vtl, mask, Obuf);
  // 6) requant O (int8 swizzled), then output projection (i8 MFMA)
  quant_rows_i8<<<TOK, 256, 0, stream>>>(Obuf, qO, sO);
  gemm_i8<0><<<dim3(CC / 128, TOK / 128, 1), 256, 0, stream>>>(
      qO, qwo, out, nullptr, nullptr, sO, swo, bo, CC, CC);
}

// Round 6
// 490.962 us; speedup vs baseline: 1.1283x; 1.0193x over previous
//
#include <hip/hip_runtime.h>
#include <cstdint>
#include <cstddef>

// ---------------------------------------------------------------------------
// QuantCrossAttention, MI355X/gfx950.  B=2 N=4096 L=512 C=2048 H=16 D=128.
// - int8 quant replicated bit-exactly (IEEE div, rintf=RNE, max-chain)
// - w8a8 GEMMs on TRUE i8 MFMA (mfma_i32_16x16x64_i8), operands XOR-swizzled
//   in GLOBAL layout so global_load_lds stages verbatim.
// - fp32 GEMMs (K/V proj, QK^T, PV) via bf16 hi/lo split, 3 MFMA terms
// R6: T14 issue-early/write-late staging in attn; 2-phase dbuf in gemm_i8.
// R7: attn reg diet (2 blocks/CU) + T1 XCD swizzle everywhere.
// R8: attn 1024-thr / 16-wave / dbuf ks+vt / ONE barrier per chunk (121 us).
// R9: gemm_kv2 fused single-K K/V projection (memset/atomics/bias-split gone).
// R10 (theory: kv2 runs at 1 block/CU where the compiler's vmcnt(0)-before-
//      barrier drain exposes full load latency every K-step, and its frag
//      reads are 8-way bank-conflicted (64B row stride, no swizzle)):
//   * gemm_kv2: reg-staged dist-2 pipeline (loads->regs: barrier needs NO
//     vmcnt drain; regs->LDS after loop-top barrier) + XOR unit-swizzle on
//     ds_write AND frag read (8-way -> 2-way=free).  Same math order =>
//     bit-identical output.
//   * launch merges: quant_w2 (wq+wo in one dispatch), split3_k
//     (cond/wk/wv in one dispatch).  10 -> 8 dispatches.
// R11: identical resubmit of R10 (bench failed on container acquisition, no
//      kernel verdict; audit found no hang/fault class — see journal).
// ---------------------------------------------------------------------------

typedef __bf16 bf16;
typedef __bf16 bf16x8 __attribute__((ext_vector_type(8)));
typedef __bf16 bf16x4 __attribute__((ext_vector_type(4)));
typedef float  f32x4  __attribute__((ext_vector_type(4)));
typedef int    i32x4  __attribute__((ext_vector_type(4)));

#define DEV __device__ __forceinline__

static constexpr int CB = 2;
static constexpr int CN = 4096;
static constexpr int CL = 512;
static constexpr int CC = 2048;
static constexpr int CH = 16;
static constexpr int CD = 128;
static constexpr int TOK = CB * CN;  // 8192 tokens
static constexpr int LR  = CB * CL;  // 1024 cond rows

DEV void gl_lds16(const void* g, void* l) {
  __builtin_amdgcn_global_load_lds(
      (const __attribute__((address_space(1))) unsigned int*)g,
      (__attribute__((address_space(3))) unsigned int*)l, 16, 0, 0);
}

DEV f32x4 mfma16(bf16x8 a, bf16x8 b, f32x4 c) {
  return __builtin_amdgcn_mfma_f32_16x16x32_bf16(a, b, c, 0, 0, 0);
}

DEV i32x4 mfma_i8(i32x4 a, i32x4 b, i32x4 c) {
  return __builtin_amdgcn_mfma_i32_16x16x64_i8(a, b, c, 0, 0, 0);
}

// --------- per-row symmetric int8 quant body (bit-exact vs np) --------------
// Output layout: within each 64B k-block, 16B unit u placed at u ^ ((row>>1)&3)
DEV void quant_row_body(const float* __restrict__ in, signed char* __restrict__ q,
                        float* __restrict__ scale, const int r, const int t)
{
  const float* x = in + (size_t)r * CC;
  const float4 v0 = ((const float4*)x)[2 * t];
  const float4 v1 = ((const float4*)x)[2 * t + 1];
  float m = fmaxf(fmaxf(fmaxf(fabsf(v0.x), fabsf(v0.y)), fmaxf(fabsf(v0.z), fabsf(v0.w))),
                  fmaxf(fmaxf(fabsf(v1.x), fabsf(v1.y)), fmaxf(fabsf(v1.z), fabsf(v1.w))));
#pragma unroll
  for (int off = 32; off > 0; off >>= 1) m = fmaxf(m, __shfl_xor(m, off));
  __shared__ float sm[4];
  if ((t & 63) == 0) sm[t >> 6] = m;
  __syncthreads();
  m = fmaxf(fmaxf(sm[0], sm[1]), fmaxf(sm[2], sm[3]));
  const float s = fmaxf(m / 127.0f, 1e-8f);   // IEEE divide: bit-matches np
  if (t == 0) scale[r] = s;
  const float a[8] = {v0.x, v0.y, v0.z, v0.w, v1.x, v1.y, v1.z, v1.w};
  int2 pk;
  int lo = 0, hi = 0;
#pragma unroll
  for (int j = 0; j < 4; j++) {
    const int b0 = (int)fminf(fmaxf(rintf(a[j]     / s), -127.f), 127.f);
    const int b1 = (int)fminf(fmaxf(rintf(a[4 + j] / s), -127.f), 127.f);
    lo |= (b0 & 255) << (8 * j);
    hi |= (b1 & 255) << (8 * j);
  }
  pk.x = lo; pk.y = hi;
  const int c0 = t * 8;
  const int f = (r >> 1) & 3;
  const int pos = (c0 & ~63) | ((((c0 >> 4) & 3) ^ f) << 4) | (c0 & 15);
  *(int2*)&q[(size_t)r * CC + pos] = pk;
}

__global__ __launch_bounds__(256) void quant_rows_i8(
    const float* __restrict__ in, signed char* __restrict__ q,
    float* __restrict__ scale)
{
  quant_row_body(in, q, scale, blockIdx.x, threadIdx.x);
}

// merged wq + wo quantization (one dispatch)
__global__ __launch_bounds__(256) void quant_w2(
    const float* __restrict__ wq, const float* __restrict__ wo,
    signed char* __restrict__ qwq, signed char* __restrict__ qwo,
    float* __restrict__ swq, float* __restrict__ swo)
{
  int r = blockIdx.x;
  if (r < CC) quant_row_body(wq, qwq, swq, r, threadIdx.x);
  else        quant_row_body(wo, qwo, swo, r - CC, threadIdx.x);
}

// --------- merged fp32 -> bf16 hi/lo splits (cond, wk, wv) ------------------
__global__ __launch_bounds__(256) void split3_k(
    const float* __restrict__ cond, const float* __restrict__ wk,
    const float* __restrict__ wv,
    bf16* __restrict__ ch,  bf16* __restrict__ cl_,
    bf16* __restrict__ wkh, bf16* __restrict__ wkl,
    bf16* __restrict__ wvh, bf16* __restrict__ wvl)
{
  const int NC = (LR * CC / 4) / 256;   // 2048 blocks (cond)
  const int NW = (CC * CC / 4) / 256;   // 4096 blocks per weight
  int blk = blockIdx.x;
  const float* in; bf16* hi; bf16* lo;
  if (blk < NC)           { in = cond; hi = ch;  lo = cl_; }
  else if (blk < NC + NW) { blk -= NC;      in = wk; hi = wkh; lo = wkl; }
  else                    { blk -= NC + NW; in = wv; hi = wvh; lo = wvl; }
  const size_t i = (size_t)blk * 256 + threadIdx.x;  // float4 index
  const float4 v = ((const float4*)in)[i];
  const float a[4] = {v.x, v.y, v.z, v.w};
  bf16x4 h4, l4;
#pragma unroll
  for (int j = 0; j < 4; j++) {
    bf16 h = (bf16)a[j];
    h4[j] = h;
    l4[j] = (bf16)(a[j] - (float)h);
  }
  ((bf16x4*)hi)[i] = h4;
  ((bf16x4*)lo)[i] = l4;
}

// --------- int8 GEMM, A[M,K] * B[Nd,K]^T, both K-major, pre-swizzled --------
// 2-phase double-buffered pipeline (one barrier per K-step) + T1 XCD swizzle.
// (grid 1024 => ~4 blocks/CU: TLP covers the barrier's vmcnt drain here.)
template <int MODE>
__global__ __launch_bounds__(256) void gemm_i8(
    const signed char* __restrict__ A, const signed char* __restrict__ B,
    float* __restrict__ out0, bf16* __restrict__ outH, bf16* __restrict__ outL,
    const float* __restrict__ rowS, const float* __restrict__ colS,
    const float* __restrict__ bias, const int Nd, const int K)
{
  __shared__ signed char sA[2][128 * 64] __attribute__((aligned(16)));
  __shared__ signed char sB[2][128 * 64] __attribute__((aligned(16)));
  const int t = threadIdx.x;
  int lin = blockIdx.y * 16 + blockIdx.x;          // grid = (16, 64) = 1024
  lin = (lin & 7) * 128 + (lin >> 3);              // XCD-contiguous logical id
  const int m0 = (lin >> 4) * 128, n0 = (lin & 15) * 128;
  const int srow = t >> 2, scol = (t & 3) * 16;   // 64 rows/instr, 16B/lane
  const signed char* aP = A + (size_t)(m0 + srow) * K + scol;
  const signed char* bP = B + (size_t)(n0 + srow) * K + scol;
  const int lane = t & 63, wave = t >> 6;
  const int wm = (wave >> 1) * 64, wn = (wave & 1) * 64;
  const int quad = lane >> 4, l16 = lane & 15;
  i32x4 acc[4][4] = {};

  // prologue: stage k-block 0 into buffer 0
  gl_lds16(aP,                  &sA[0][t * 16]);
  gl_lds16(aP + (size_t)64 * K, &sA[0][4096 + t * 16]);
  gl_lds16(bP,                  &sB[0][t * 16]);
  gl_lds16(bP + (size_t)64 * K, &sB[0][4096 + t * 16]);
  __syncthreads();

  int cur = 0;
  for (int kb = 0; kb < K; kb += 64) {
    const int nx = kb + 64;
    if (nx < K) {   // stage next k-block into the other buffer (async)
      gl_lds16(aP + nx,                  &sA[cur ^ 1][t * 16]);
      gl_lds16(aP + nx + (size_t)64 * K, &sA[cur ^ 1][4096 + t * 16]);
      gl_lds16(bP + nx,                  &sB[cur ^ 1][t * 16]);
      gl_lds16(bP + nx + (size_t)64 * K, &sB[cur ^ 1][4096 + t * 16]);
    }
    i32x4 fa[4], fb[4];
#pragma unroll
    for (int i = 0; i < 4; i++) {
      const int ra = wm + i * 16 + l16;
      const int rb = wn + i * 16 + l16;
      fa[i] = *(const i32x4*)&sA[cur][ra * 64 + (quad ^ ((ra >> 1) & 3)) * 16];
      fb[i] = *(const i32x4*)&sB[cur][rb * 64 + (quad ^ ((rb >> 1) & 3)) * 16];
    }
#pragma unroll
    for (int mt = 0; mt < 4; mt++)
#pragma unroll
      for (int nt = 0; nt < 4; nt++)
        acc[mt][nt] = mfma_i8(fa[mt], fb[nt], acc[mt][nt]);
    __syncthreads();   // drains vmcnt(0): buf^1 staged; lgkm: buf reads done
    cur ^= 1;
  }

  // epilogue: C/D layout col=lane&15, row=quad*4+reg (shape-determined)
#pragma unroll
  for (int mt = 0; mt < 4; mt++)
#pragma unroll
    for (int nt = 0; nt < 4; nt++)
#pragma unroll
      for (int rg = 0; rg < 4; rg++) {
        const int mr = m0 + wm + mt * 16 + quad * 4 + rg;
        const int nc = n0 + wn + nt * 16 + l16;
        const float a = (float)acc[mt][nt][rg];
        const float sc = rowS[mr] * colS[nc];   // (sx*sw) first: matches np
        const float v = a * sc + bias[nc];
        if (MODE == 0) {
          out0[(size_t)mr * Nd + nc] = v;
        } else {
          const bf16 h = (bf16)v;
          outH[(size_t)mr * Nd + nc] = h;
          outL[(size_t)mr * Nd + nc] = (bf16)(v - (float)h);
        }
      }
}

// --------- bf16-split GEMM for K/V projections, fully fused -----------------
// R10: reg-staged dist-2 pipeline (1 block/CU: reg loads avoid the barrier
// vmcnt drain entirely — R8 attn pattern) + XOR unit-swizzle on LDS write
// and frag read (kills the 8-way 64B-stride bank conflict).  Epilogue fuses
// bias + hi/lo split (+ V LDS-transpose).  Math order identical to R9.
__global__ __launch_bounds__(256) void gemm_kv2(
    const bf16* __restrict__ Ah, const bf16* __restrict__ Al,
    const bf16* __restrict__ B0h, const bf16* __restrict__ B0l,
    const bf16* __restrict__ B1h, const bf16* __restrict__ B1l,
    bf16* __restrict__ outKh, bf16* __restrict__ outKl,
    bf16* __restrict__ outVh, bf16* __restrict__ outVl,
    const float* __restrict__ bk, const float* __restrict__ bv)
{
  // arena: 4 staging arrays x [2 dbuf][128*32] bf16 (16 KiB each) = 64 KiB;
  // epilogue V-transpose tile [128][129] fp32 = 66048 B aliases it.
  __shared__ char arena[128 * 129 * 4] __attribute__((aligned(16)));
  bf16 (*sAh)[4096] = (bf16 (*)[4096])(arena);
  bf16 (*sBh)[4096] = (bf16 (*)[4096])(arena + 16384);
  bf16 (*sAl)[4096] = (bf16 (*)[4096])(arena + 32768);
  bf16 (*sBl)[4096] = (bf16 (*)[4096])(arena + 49152);
  const int t = threadIdx.x;
  const int K = CC;
  int lin = (blockIdx.z * 8 + blockIdx.y) * 16 + blockIdx.x;  // 256 blocks
  lin = (lin & 7) * 32 + (lin >> 3);                          // XCD swizzle
  const int n0 = (lin & 15) * 128;
  const int m0 = ((lin >> 4) & 7) * 128;
  const int kv = lin >> 7;
  const bf16* Bh = kv ? B1h : B0h;
  const bf16* Bl = kv ? B1l : B0l;
  const int srow = t >> 2, c8 = t & 3, scol = c8 * 8;
  // swizzled LDS elem offsets for this thread's two staged rows
  const int r1 = srow + 64;
  const int d0 = srow * 32 + ((c8 ^ ((srow >> 1) & 3)) * 8);
  const int d1 = r1   * 32 + ((c8 ^ ((r1   >> 1) & 3)) * 8);
  const bf16* aP  = Ah + (size_t)(m0 + srow) * K + scol;
  const bf16* bP  = Bh + (size_t)(n0 + srow) * K + scol;
  const bf16* aPl = Al + (size_t)(m0 + srow) * K + scol;
  const bf16* bPl = Bl + (size_t)(n0 + srow) * K + scol;
  const int lane = t & 63, wave = t >> 6;
  const int wm = (wave >> 1) * 64, wn = (wave & 1) * 64;
  const int quad = lane >> 4, l16 = lane & 15;
  f32x4 acc[4][4] = {};

  uint4 g0, g1, g2, g3, g4, g5, g6, g7;   // in-flight K-step (reg staging)
#define KV_LOAD(kb)                                                 \
  do {                                                              \
    g0 = *(const uint4*)(aP  + (kb));                               \
    g1 = *(const uint4*)(aP  + (kb) + (size_t)64 * K);              \
    g2 = *(const uint4*)(bP  + (kb));                               \
    g3 = *(const uint4*)(bP  + (kb) + (size_t)64 * K);              \
    g4 = *(const uint4*)(aPl + (kb));                               \
    g5 = *(const uint4*)(aPl + (kb) + (size_t)64 * K);              \
    g6 = *(const uint4*)(bPl + (kb));                               \
    g7 = *(const uint4*)(bPl + (kb) + (size_t)64 * K);              \
  } while (0)
#define KV_WRITE(buf)                                               \
  do {                                                              \
    *(uint4*)&sAh[buf][d0] = g0;  *(uint4*)&sAh[buf][d1] = g1;      \
    *(uint4*)&sBh[buf][d0] = g2;  *(uint4*)&sBh[buf][d1] = g3;      \
    *(uint4*)&sAl[buf][d0] = g4;  *(uint4*)&sAl[buf][d1] = g5;      \
    *(uint4*)&sBl[buf][d0] = g6;  *(uint4*)&sBl[buf][d1] = g7;      \
  } while (0)

  // pipeline prologue: step0 -> LDS buf0; step1 -> regs
  KV_LOAD(0);
  KV_WRITE(0);
  KV_LOAD(32);

  const int NS = K / 32;   // 64 K-steps
  for (int ci = 0; ci < NS; ci++) {
    const int cur = ci & 1;
    __syncthreads();   // closes step ci-1 reads of buf^1 (no vmcnt coupling)
    if (ci + 1 < NS) KV_WRITE(cur ^ 1);          // regs -> other buffer
    if (ci + 2 < NS) KV_LOAD((ci + 2) * 32);     // issue-early prefetch
    bf16x8 fa[4], fb[4], fal[4], fbl[4];
#pragma unroll
    for (int i = 0; i < 4; i++) {
      const int ra = wm + i * 16 + l16;
      const int rb = wn + i * 16 + l16;
      const int oa = ra * 32 + ((quad ^ ((ra >> 1) & 3)) * 8);
      const int ob = rb * 32 + ((quad ^ ((rb >> 1) & 3)) * 8);
      fa[i]  = *(const bf16x8*)&sAh[cur][oa];
      fb[i]  = *(const bf16x8*)&sBh[cur][ob];
      fal[i] = *(const bf16x8*)&sAl[cur][oa];
      fbl[i] = *(const bf16x8*)&sBl[cur][ob];
    }
#pragma unroll
    for (int mt = 0; mt < 4; mt++)
#pragma unroll
      for (int nt = 0; nt < 4; nt++) {
        f32x4 c = acc[mt][nt];
        c = mfma16(fa[mt],  fb[nt],  c);
        c = mfma16(fa[mt],  fbl[nt], c);
        c = mfma16(fal[mt], fb[nt],  c);
        acc[mt][nt] = c;
      }
  }
#undef KV_LOAD
#undef KV_WRITE

  if (kv == 0) {
    // ---- K path: bias + hi/lo split, direct store ----
#pragma unroll
    for (int mt = 0; mt < 4; mt++)
#pragma unroll
      for (int nt = 0; nt < 4; nt++)
#pragma unroll
        for (int rg = 0; rg < 4; rg++) {
          const int mr = m0 + wm + mt * 16 + quad * 4 + rg;
          const int nc = n0 + wn + nt * 16 + l16;
          const float v = acc[mt][nt][rg] + bk[nc];
          const bf16 h = (bf16)v;
          outKh[(size_t)mr * CC + nc] = h;
          outKl[(size_t)mr * CC + nc] = (bf16)(v - (float)h);
        }
  } else {
    // ---- V path: bias -> LDS tile -> transpose -> hi/lo split ----
    __syncthreads();   // all waves done with staging buffers (kv uniform/block)
    float (*tile)[129] = (float (*)[129])arena;   // aliases staging
#pragma unroll
    for (int mt = 0; mt < 4; mt++)
#pragma unroll
      for (int nt = 0; nt < 4; nt++)
#pragma unroll
        for (int rg = 0; rg < 4; rg++) {
          const int lm = wm + mt * 16 + quad * 4 + rg;
          const int ln = wn + nt * 16 + l16;
          tile[lm][ln] = acc[mt][nt][rg] + bv[n0 + ln];
        }
    __syncthreads();
    // n0 spans exactly one head (BN = CD = 128); m0 spans one b (128 | 512)
    const int h = n0 >> 7, b = m0 >> 9, lbase = m0 & (CL - 1);
    const int d = t & 127, half = t >> 7;      // 256 thr: 128 d x 2 l-halves
    const size_t orow = ((size_t)(b * CH + h) * CD + d) * CL + lbase + half * 64;
#pragma unroll
    for (int jv = 0; jv < 8; jv++) {
      bf16x8 h8, l8;
#pragma unroll
      for (int j = 0; j < 8; j++) {
        const float v = tile[half * 64 + jv * 8 + j][d];
        const bf16 hh = (bf16)v;
        h8[j] = hh;
        l8[j] = (bf16)(v - (float)hh);
      }
      *(bf16x8*)&outVh[orow + jv * 8] = h8;
      *(bf16x8*)&outVl[orow + jv * 8] = l8;
    }
  }
}

// --------- flash attention, split-bf16, MAX-FREE softmax --------------------
// R8: 1024 thr / 16 waves / 256 Q rows; ONE block per CU.  ks+vt both
// double-buffered; prefetch distance 2; ONE barrier per chunk.
__global__ __launch_bounds__(1024, 4) void attn_k(
    const bf16* __restrict__ qh, const bf16* __restrict__ ql,
    const bf16* __restrict__ kh, const bf16* __restrict__ kl,
    const bf16* __restrict__ vth, const bf16* __restrict__ vtl,
    const float* __restrict__ mask, float* __restrict__ O)
{
  // arena: ks [2][2][32][136] (34816 B) | vt [2][2][128][32] (32768 B)
  //        | ps [16][16][36] (36864 B)  = 104448 B
  __shared__ char arena[34816 + 32768 + 36864] __attribute__((aligned(16)));
  bf16 (*ksb)[2][32][136] = (bf16 (*)[2][32][136])arena;           // [dbuf][hilo]
  bf16 (*vtb)[2][128][32] = (bf16 (*)[2][128][32])(arena + 34816); // [dbuf][hilo]
  float (*ps)[16][36] = (float (*)[16][36])(arena + 34816 + 32768);
  const int t = threadIdx.x, lane = t & 63, w = t >> 6;   // w in 0..15
  const int quad = lane >> 4, l16 = lane & 15;
  int lin = (blockIdx.z * 16 + blockIdx.y) * 16 + blockIdx.x;  // (16,16,2)=512
  lin = (lin & 7) * 64 + (lin >> 3);                           // XCD swizzle
  const int n0 = (lin & 15) * 256;
  const int h  = (lin >> 4) & 15;
  const int b  = lin >> 8;
  const int bh = b * CH + h;
  const size_t qrow0 = (size_t)b * CN + n0;
  const float* mrow_base = mask + ((size_t)b * CN + n0 + w * 16 + quad * 4) * CL;

  // ---- staging-lane geometry (1024 thr: plane = hi/lo by t>>9) ----
  const int pl   = t >> 9;                       // 0 = hi, 1 = lo
  const int krow = (t >> 4) & 31, ksg = t & 15;  // K: 32 l-rows x 128 d, 16B
  const int vrow = (t >> 2) & 127, vsg = t & 3;  // V^T: 128 d-rows x 32 l, 16B
  const bf16* kPsrc = pl ? kl : kh;
  const bf16* vPsrc = pl ? vtl : vth;
  const int vc = (vsg ^ ((vrow >> 3) & 3)) * 8;  // XOR chunk swizzle (fixed)
  uint4 kr, vr;
  // chunk-0 prefetch (overlaps Q preamble)
  kr = *(const uint4*)(kPsrc + ((size_t)b * CL + krow) * CC + h * CD + ksg * 8);
  vr = *(const uint4*)(vPsrc + ((size_t)bh * CD + vrow) * CL + vsg * 8);

  // ---- Q fragments into registers (staged via arena for coalescing) ----
  bf16x8 qfh[4], qfl[4];
  {
    bf16* qs = (bf16*)arena;   // 256 rows x 136 = 69632 B (ps not yet live)
    const int row = t >> 2, sg = t & 3;
    {
      const bf16* src = qh + (qrow0 + row) * CC + h * CD + sg * 32;
      bf16* dst = qs + row * 136 + sg * 32;
#pragma unroll
      for (int j = 0; j < 4; j++) ((uint4*)dst)[j] = ((const uint4*)src)[j];
    }
    __syncthreads();
#pragma unroll
    for (int s = 0; s < 4; s++)
      qfh[s] = *(const bf16x8*)&qs[(w * 16 + l16) * 136 + s * 32 + quad * 8];
    __syncthreads();
    {
      const bf16* src = ql + (qrow0 + row) * CC + h * CD + sg * 32;
      bf16* dst = qs + row * 136 + sg * 32;
#pragma unroll
      for (int j = 0; j < 4; j++) ((uint4*)dst)[j] = ((const uint4*)src)[j];
    }
    __syncthreads();
#pragma unroll
    for (int s = 0; s < 4; s++)
      qfl[s] = *(const bf16x8*)&qs[(w * 16 + l16) * 136 + s * 32 + quad * 8];
    __syncthreads();   // qs reads done; arena now owned by ks/vt/ps
  }

  // ---- pipeline prologue: write chunk0 -> buf0; load chunk1 regs ----
  *(uint4*)&ksb[0][pl][krow][ksg * 8] = kr;
  *(uint4*)&vtb[0][pl][vrow][vc] = vr;
  kr = *(const uint4*)(kPsrc + ((size_t)b * CL + 32 + krow) * CC + h * CD + ksg * 8);
  vr = *(const uint4*)(vPsrc + ((size_t)bh * CD + vrow) * CL + 32 + vsg * 8);

  f32x4 oacc[8] = {};
  f32x4 suma = {};          // row-sum accumulator (MFMA ones-trick)
  const bf16 one = (bf16)1.0f;
  const bf16x8 ones = {one, one, one, one, one, one, one, one};
  const float isd = 0.08838834764831845f;   // np.float32(1/sqrt(128))

  for (int ci = 0; ci < CL / 32; ci++) {
    const int cur = ci & 1;
    __syncthreads();   // closes chunk ci-1 reads of buf^1; buf[cur] visible
    // ---- write-late: chunk ci+1 regs -> other buffer (overlaps compute) --
    if (ci + 1 < CL / 32) {
      *(uint4*)&ksb[cur ^ 1][pl][krow][ksg * 8] = kr;
      *(uint4*)&vtb[cur ^ 1][pl][vrow][vc] = vr;
    }
    // ---- issue-early: chunk ci+2 prefetch (full chunk of latency cover) --
    if (ci + 2 < CL / 32) {
      const int lcn = (ci + 2) * 32;
      kr = *(const uint4*)(kPsrc + ((size_t)b * CL + lcn + krow) * CC + h * CD + ksg * 8);
      vr = *(const uint4*)(vPsrc + ((size_t)bh * CD + vrow) * CL + lcn + vsg * 8);
    }
    // ---- current-chunk mask loads (QK covers the latency) ----------------
    const int lc = ci * 32;
    float mcur[2][4];
#pragma unroll
    for (int rg = 0; rg < 4; rg++) {
      const float* mrp = mrow_base + (size_t)rg * CL + lc;
      mcur[0][rg] = mrp[l16];
      mcur[1][rg] = mrp[16 + l16];
    }

    // ---- S = Q K^T (split, 3 terms), two 16x16 l-tiles -------------------
    f32x4 sacc[2] = {};
    __builtin_amdgcn_s_setprio(1);
#pragma unroll
    for (int s = 0; s < 4; s++) {
#pragma unroll
      for (int lt = 0; lt < 2; lt++) {
        bf16x8 kbh = *(const bf16x8*)&ksb[cur][0][lt * 16 + l16][s * 32 + quad * 8];
        bf16x8 kbl = *(const bf16x8*)&ksb[cur][1][lt * 16 + l16][s * 32 + quad * 8];
        sacc[lt] = mfma16(qfh[s], kbh, sacc[lt]);
        sacc[lt] = mfma16(qfh[s], kbl, sacc[lt]);
        sacc[lt] = mfma16(qfl[s], kbh, sacc[lt]);
      }
    }
    __builtin_amdgcn_s_setprio(0);

    // ---- MAX-FREE softmax: u = exp(s*isd + mask); sum rides MFMA ---------
    float u[2][4];
#pragma unroll
    for (int rg = 0; rg < 4; rg++) {
      u[0][rg] = __expf(sacc[0][rg] * isd + mcur[0][rg]);
      u[1][rg] = __expf(sacc[1][rg] * isd + mcur[1][rg]);
    }

    // ---- P: C-layout -> A-layout via wave-private LDS round-trip ---------
#pragma unroll
    for (int lt = 0; lt < 2; lt++)
#pragma unroll
      for (int rg = 0; rg < 4; rg++)
        ps[w][quad * 4 + rg][lt * 16 + l16] = u[lt][rg];
    const float4 p0 = *(const float4*)&ps[w][l16][quad * 8];
    const float4 p1 = *(const float4*)&ps[w][l16][quad * 8 + 4];
    const float pv[8] = {p0.x, p0.y, p0.z, p0.w, p1.x, p1.y, p1.z, p1.w};
    bf16x8 ph, plv;
#pragma unroll
    for (int j = 0; j < 8; j++) {
      bf16 hh = (bf16)pv[j];
      ph[j] = hh;
      plv[j] = (bf16)(pv[j] - (float)hh);
    }

    // ---- O += P V (split, 3 terms) + row-sum channel ---------------------
    suma = mfma16(ph, ones, suma);
    suma = mfma16(plv, ones, suma);
    __builtin_amdgcn_s_setprio(1);
#pragma unroll
    for (int nt = 0; nt < 8; nt++) {
      const int vrr = nt * 16 + l16;
      const int vsw = (quad ^ ((vrr >> 3) & 3)) * 8;   // match staging swizzle
      bf16x8 vbh = *(const bf16x8*)&vtb[cur][0][vrr][vsw];
      bf16x8 vbl = *(const bf16x8*)&vtb[cur][1][vrr][vsw];
      f32x4 c = oacc[nt];
      c = mfma16(ph, vbh, c);
      c = mfma16(ph, vbl, c);
      c = mfma16(plv, vbh, c);
      oacc[nt] = c;
    }
    __builtin_amdgcn_s_setprio(0);
  }

  // ---- epilogue: O / sum ----------------------------------------------------
  f32x4 inv;
#pragma unroll
  for (int rg = 0; rg < 4; rg++) inv[rg] = 1.0f / suma[rg];
#pragma unroll
  for (int nt = 0; nt < 8; nt++)
#pragma unroll
    for (int rg = 0; rg < 4; rg++) {
      const size_t row = qrow0 + w * 16 + quad * 4 + rg;
      O[row * CC + h * CD + nt * 16 + l16] = oacc[nt][rg] * inv[rg];
    }
}

// ---------------------------------------------------------------------------
extern "C" void kernel_launch(void* const* d_in, const int* in_sizes, int n_in,
                              void* d_out, int out_size, void* d_ws, size_t ws_size,
                              hipStream_t stream)
{
  (void)in_sizes; (void)n_in; (void)out_size; (void)ws_size;
  const float* x    = (const float*)d_in[0];
  const float* cond = (const float*)d_in[1];
  const float* mask = (const float*)d_in[2];
  const float* wq   = (const float*)d_in[3];
  const float* bq   = (const float*)d_in[4];
  const float* wk   = (const float*)d_in[5];
  const float* bk   = (const float*)d_in[6];
  const float* wv   = (const float*)d_in[7];
  const float* bv   = (const float*)d_in[8];
  const float* wo   = (const float*)d_in[9];
  const float* bo   = (const float*)d_in[10];
  float* out = (float*)d_out;

  char* wsb = (char*)d_ws;
  size_t off = 0;
  auto alloc = [&](size_t bytes) -> char* {
    char* p = wsb + off;
    off += (bytes + 255) & ~(size_t)255;
    return p;
  };
  // Region 1 (dead before attention; Obuf 64 MiB aliases qx..wvl)
  signed char* qx  = (signed char*)alloc((size_t)TOK * CC);  // 16 MiB
  signed char* qwq = (signed char*)alloc((size_t)CC * CC);   //  4 MiB
  bf16* ch  = (bf16*)alloc((size_t)LR * CC * 2);   //  4 MiB
  bf16* cl_ = (bf16*)alloc((size_t)LR * CC * 2);   //  4 MiB
  bf16* wkh = (bf16*)alloc((size_t)CC * CC * 2);   //  8 MiB
  bf16* wkl = (bf16*)alloc((size_t)CC * CC * 2);   //  8 MiB
  bf16* wvh = (bf16*)alloc((size_t)CC * CC * 2);   //  8 MiB
  bf16* wvl = (bf16*)alloc((size_t)CC * CC * 2);   //  8 MiB
  (void)alloc((size_t)16 << 20);                   // 16 MiB spacer (Obuf tail)
  float* Obuf = (float*)qx;                        // alias: 64 MiB over qx..spacer
  // Region 2 (live through attention)
  bf16* qhb = (bf16*)alloc((size_t)TOK * CC * 2);  // 32 MiB (later reused as qO)
  bf16* qlb = (bf16*)alloc((size_t)TOK * CC * 2);  // 32 MiB
  bf16* khb = (bf16*)alloc((size_t)LR * CC * 2);
  bf16* klb = (bf16*)alloc((size_t)LR * CC * 2);
  bf16* vth = (bf16*)alloc((size_t)LR * CC * 2);   // V^T [b,h,d,l] hi
  bf16* vtl = (bf16*)alloc((size_t)LR * CC * 2);   // V^T [b,h,d,l] lo
  signed char* qwo = (signed char*)alloc((size_t)CC * CC);
  float* sx  = (float*)alloc((size_t)TOK * 4);
  float* swq = (float*)alloc((size_t)CC * 4);
  float* swo = (float*)alloc((size_t)CC * 4);
  float* sO  = (float*)alloc((size_t)TOK * 4);
  signed char* qO = (signed char*)qhb;   // alias: qh/ql dead after attention

  // 1) quantize weights (merged) and x (int8, swizzled for gemm_i8)
  quant_w2<<<2 * CC, 256, 0, stream>>>(wq, wo, qwq, qwo, swq, swo);
  quant_rows_i8<<<TOK, 256, 0, stream>>>(x, qx, sx);
  // 2) split fp32 inputs for the fp32-emulated GEMMs (merged)
  split3_k<<<(LR * CC / 4) / 256 + 2 * ((CC * CC / 4) / 256), 256, 0, stream>>>(
      cond, wk, wv, ch, cl_, wkh, wkl, wvh, wvl);
  // 3) Q = dequant(qx @ qwq^T) + bq, written as bf16 hi/lo split  (i8 MFMA)
  gemm_i8<1><<<dim3(CC / 128, TOK / 128, 1), 256, 0, stream>>>(
      qx, qwq, nullptr, qhb, qlb, sx, swq, bq, CC, CC);
  // 4) K/V projections: reg-staged dbuf GEMM, fused bias+split(+V transpose)
  gemm_kv2<<<dim3(CC / 128, LR / 128, 2), 256, 0, stream>>>(
      ch, cl_, wkh, wkl, wvh, wvl, khb, klb, vth, vtl, bk, bv);
  // 5) attention: 256-row Q tiles, 1024 threads, 1-barrier dbuf pipeline
  attn_k<<<dim3(CN / 256, CH, CB), 1024, 0, stream>>>(
      qhb, qlb, khb, klb, vth, vtl, mask, Obuf);
  // 6) requant O (int8 swizzled), then output projection (i8 MFMA)
  quant_rows_i8<<<TOK, 256, 0, stream>>>(Obuf, qO, sO);
  gemm_i8<0><<<dim3(CC / 128, TOK / 128, 1), 256, 0, stream>>>(
      qO, qwo, out, nullptr, nullptr, sO, swo, bo, CC, CC);
}

// Round 7
// 471.242 us; speedup vs baseline: 1.1755x; 1.0418x over previous
//
#include <hip/hip_runtime.h>
#include <cstdint>
#include <cstddef>

// ---------------------------------------------------------------------------
// QuantCrossAttention, MI355X/gfx950.  B=2 N=4096 L=512 C=2048 H=16 D=128.
// - int8 quant replicated bit-exactly (IEEE div, rintf=RNE, max-chain)
// - w8a8 GEMMs on TRUE i8 MFMA (mfma_i32_16x16x64_i8), operands XOR-swizzled
//   in GLOBAL layout so staging places them verbatim.
// - fp32 GEMMs (K/V proj, QK^T, PV) via bf16 hi/lo split, 3 MFMA terms
// R6:  T14 staging in attn; 2-phase dbuf in gemm_i8.
// R7:  attn reg diet + T1 XCD swizzle everywhere.
// R8:  attn 1024-thr / 16-wave / dbuf ks+vt / ONE barrier per chunk (119 us).
// R9:  gemm_kv2 fused single-K K/V projection.
// R10: gemm_kv2 reg-staged dist-2 + LDS XOR swizzle; launch merges.
// R12 (theory: gemm_i8's gl_lds16 couples prefetch to the barrier's vmcnt(0)
//      drain — 200-500 exposed cycles x 32 K-steps, the same stall class
//      removed from attn(R8)/kv2(R10)):
//   * gemm_i8: reg-staged dist-2 pipeline (loads->regs, write buf^1 after
//     loop-top barrier, prefetch k+2).  launch_bounds(256,4) pins <=128 VGPR
//     (4 blocks/CU).  Same math order => bit-identical output.
//   * prep_k: quant(x) + quant(wq,wo) + split(cond,wk,wv) in ONE dispatch
//     (8 -> 6 dispatches).
// ---------------------------------------------------------------------------

typedef __bf16 bf16;
typedef __bf16 bf16x8 __attribute__((ext_vector_type(8)));
typedef __bf16 bf16x4 __attribute__((ext_vector_type(4)));
typedef float  f32x4  __attribute__((ext_vector_type(4)));
typedef int    i32x4  __attribute__((ext_vector_type(4)));

#define DEV __device__ __forceinline__

static constexpr int CB = 2;
static constexpr int CN = 4096;
static constexpr int CL = 512;
static constexpr int CC = 2048;
static constexpr int CH = 16;
static constexpr int CD = 128;
static constexpr int TOK = CB * CN;  // 8192 tokens
static constexpr int LR  = CB * CL;  // 1024 cond rows

DEV f32x4 mfma16(bf16x8 a, bf16x8 b, f32x4 c) {
  return __builtin_amdgcn_mfma_f32_16x16x32_bf16(a, b, c, 0, 0, 0);
}

DEV i32x4 mfma_i8(i32x4 a, i32x4 b, i32x4 c) {
  return __builtin_amdgcn_mfma_i32_16x16x64_i8(a, b, c, 0, 0, 0);
}

// --------- per-row symmetric int8 quant body (bit-exact vs np) --------------
// Output layout: within each 64B k-block, 16B unit u placed at u ^ ((row>>1)&3)
DEV void quant_row_body(const float* __restrict__ in, signed char* __restrict__ q,
                        float* __restrict__ scale, const int r, const int t)
{
  const float* x = in + (size_t)r * CC;
  const float4 v0 = ((const float4*)x)[2 * t];
  const float4 v1 = ((const float4*)x)[2 * t + 1];
  float m = fmaxf(fmaxf(fmaxf(fabsf(v0.x), fabsf(v0.y)), fmaxf(fabsf(v0.z), fabsf(v0.w))),
                  fmaxf(fmaxf(fabsf(v1.x), fabsf(v1.y)), fmaxf(fabsf(v1.z), fabsf(v1.w))));
#pragma unroll
  for (int off = 32; off > 0; off >>= 1) m = fmaxf(m, __shfl_xor(m, off));
  __shared__ float sm[4];
  if ((t & 63) == 0) sm[t >> 6] = m;
  __syncthreads();
  m = fmaxf(fmaxf(sm[0], sm[1]), fmaxf(sm[2], sm[3]));
  const float s = fmaxf(m / 127.0f, 1e-8f);   // IEEE divide: bit-matches np
  if (t == 0) scale[r] = s;
  const float a[8] = {v0.x, v0.y, v0.z, v0.w, v1.x, v1.y, v1.z, v1.w};
  int2 pk;
  int lo = 0, hi = 0;
#pragma unroll
  for (int j = 0; j < 4; j++) {
    const int b0 = (int)fminf(fmaxf(rintf(a[j]     / s), -127.f), 127.f);
    const int b1 = (int)fminf(fmaxf(rintf(a[4 + j] / s), -127.f), 127.f);
    lo |= (b0 & 255) << (8 * j);
    hi |= (b1 & 255) << (8 * j);
  }
  pk.x = lo; pk.y = hi;
  const int c0 = t * 8;
  const int f = (r >> 1) & 3;
  const int pos = (c0 & ~63) | ((((c0 >> 4) & 3) ^ f) << 4) | (c0 & 15);
  *(int2*)&q[(size_t)r * CC + pos] = pk;
}

__global__ __launch_bounds__(256) void quant_rows_i8(
    const float* __restrict__ in, signed char* __restrict__ q,
    float* __restrict__ scale)
{
  quant_row_body(in, q, scale, blockIdx.x, threadIdx.x);
}

DEV void split_body(const float* __restrict__ in, bf16* __restrict__ hi,
                    bf16* __restrict__ lo, const int blk, const int t)
{
  const size_t i = (size_t)blk * 256 + t;  // float4 index
  const float4 v = ((const float4*)in)[i];
  const float a[4] = {v.x, v.y, v.z, v.w};
  bf16x4 h4, l4;
#pragma unroll
  for (int j = 0; j < 4; j++) {
    bf16 h = (bf16)a[j];
    h4[j] = h;
    l4[j] = (bf16)(a[j] - (float)h);
  }
  ((bf16x4*)hi)[i] = h4;
  ((bf16x4*)lo)[i] = l4;
}

// --------- merged preprocessing: all quants + all splits, ONE dispatch ------
__global__ __launch_bounds__(256) void prep_k(
    const float* __restrict__ x,  const float* __restrict__ wq,
    const float* __restrict__ wo, const float* __restrict__ cond,
    const float* __restrict__ wk, const float* __restrict__ wv,
    signed char* __restrict__ qx, signed char* __restrict__ qwq,
    signed char* __restrict__ qwo,
    float* __restrict__ sx, float* __restrict__ swq, float* __restrict__ swo,
    bf16* __restrict__ ch,  bf16* __restrict__ cl_,
    bf16* __restrict__ wkh, bf16* __restrict__ wkl,
    bf16* __restrict__ wvh, bf16* __restrict__ wvl)
{
  const int t = threadIdx.x;
  const int NC = (LR * CC / 4) / 256;   // 2048 split-blocks (cond)
  const int NW = (CC * CC / 4) / 256;   // 4096 split-blocks per weight
  int blk = blockIdx.x;
  if (blk < TOK)        { quant_row_body(x,  qx,  sx,  blk, t); return; }
  blk -= TOK;
  if (blk < CC)         { quant_row_body(wq, qwq, swq, blk, t); return; }
  blk -= CC;
  if (blk < CC)         { quant_row_body(wo, qwo, swo, blk, t); return; }
  blk -= CC;
  if (blk < NC)         { split_body(cond, ch,  cl_, blk, t); return; }
  blk -= NC;
  if (blk < NW)         { split_body(wk,   wkh, wkl, blk, t); return; }
  blk -= NW;
  split_body(wv, wvh, wvl, blk, t);
}

// --------- int8 GEMM, A[M,K] * B[Nd,K]^T, both K-major, pre-swizzled --------
// R12: reg-staged dist-2 pipeline (loads->regs decouple from the barrier's
// vmcnt drain; write-late into buf^1; prefetch k+2) + T1 XCD swizzle.
// launch_bounds(256,4): <=128 VGPR => 4 blocks/CU retained.
template <int MODE>
__global__ __launch_bounds__(256, 4) void gemm_i8(
    const signed char* __restrict__ A, const signed char* __restrict__ B,
    float* __restrict__ out0, bf16* __restrict__ outH, bf16* __restrict__ outL,
    const float* __restrict__ rowS, const float* __restrict__ colS,
    const float* __restrict__ bias, const int Nd, const int K)
{
  __shared__ signed char sA[2][128 * 64] __attribute__((aligned(16)));
  __shared__ signed char sB[2][128 * 64] __attribute__((aligned(16)));
  const int t = threadIdx.x;
  int lin = blockIdx.y * 16 + blockIdx.x;          // grid = (16, 64) = 1024
  lin = (lin & 7) * 128 + (lin >> 3);              // XCD-contiguous logical id
  const int m0 = (lin >> 4) * 128, n0 = (lin & 15) * 128;
  const int srow = t >> 2, scol = (t & 3) * 16;   // 2 rows x 16B per thread
  const signed char* aP = A + (size_t)(m0 + srow) * K + scol;
  const signed char* bP = B + (size_t)(n0 + srow) * K + scol;
  const int lane = t & 63, wave = t >> 6;
  const int wm = (wave >> 1) * 64, wn = (wave & 1) * 64;
  const int quad = lane >> 4, l16 = lane & 15;
  i32x4 acc[4][4] = {};

  uint4 ga0, ga1, gb0, gb1;   // in-flight K-step (reg staging)
#define I8_LOAD(kb)                                          \
  do {                                                       \
    ga0 = *(const uint4*)(aP + (kb));                        \
    ga1 = *(const uint4*)(aP + (kb) + (size_t)64 * K);       \
    gb0 = *(const uint4*)(bP + (kb));                        \
    gb1 = *(const uint4*)(bP + (kb) + (size_t)64 * K);       \
  } while (0)
#define I8_WRITE(buf)                                        \
  do {                                                       \
    *(uint4*)&sA[buf][t * 16]        = ga0;                  \
    *(uint4*)&sA[buf][4096 + t * 16] = ga1;                  \
    *(uint4*)&sB[buf][t * 16]        = gb0;                  \
    *(uint4*)&sB[buf][4096 + t * 16] = gb1;                  \
  } while (0)

  // pipeline prologue: step0 -> LDS buf0; step1 -> regs
  I8_LOAD(0);
  I8_WRITE(0);
  I8_LOAD(64);

  const int NS = K / 64;   // 32 K-steps
  for (int ci = 0; ci < NS; ci++) {
    const int cur = ci & 1;
    __syncthreads();   // closes step ci-1 reads of buf^1 (no vmcnt coupling)
    if (ci + 1 < NS) I8_WRITE(cur ^ 1);          // regs -> other buffer
    if (ci + 2 < NS) I8_LOAD((ci + 2) * 64);     // issue-early prefetch
    i32x4 fa[4], fb[4];
#pragma unroll
    for (int i = 0; i < 4; i++) {
      const int ra = wm + i * 16 + l16;
      const int rb = wn + i * 16 + l16;
      fa[i] = *(const i32x4*)&sA[cur][ra * 64 + (quad ^ ((ra >> 1) & 3)) * 16];
      fb[i] = *(const i32x4*)&sB[cur][rb * 64 + (quad ^ ((rb >> 1) & 3)) * 16];
    }
#pragma unroll
    for (int mt = 0; mt < 4; mt++)
#pragma unroll
      for (int nt = 0; nt < 4; nt++)
        acc[mt][nt] = mfma_i8(fa[mt], fb[nt], acc[mt][nt]);
  }
#undef I8_LOAD
#undef I8_WRITE

  // epilogue: C/D layout col=lane&15, row=quad*4+reg (shape-determined)
#pragma unroll
  for (int mt = 0; mt < 4; mt++)
#pragma unroll
    for (int nt = 0; nt < 4; nt++)
#pragma unroll
      for (int rg = 0; rg < 4; rg++) {
        const int mr = m0 + wm + mt * 16 + quad * 4 + rg;
        const int nc = n0 + wn + nt * 16 + l16;
        const float a = (float)acc[mt][nt][rg];
        const float sc = rowS[mr] * colS[nc];   // (sx*sw) first: matches np
        const float v = a * sc + bias[nc];
        if (MODE == 0) {
          out0[(size_t)mr * Nd + nc] = v;
        } else {
          const bf16 h = (bf16)v;
          outH[(size_t)mr * Nd + nc] = h;
          outL[(size_t)mr * Nd + nc] = (bf16)(v - (float)h);
        }
      }
}

// --------- bf16-split GEMM for K/V projections, fully fused -----------------
// R10: reg-staged dist-2 pipeline + XOR unit-swizzle on LDS write and frag
// read.  Epilogue fuses bias + hi/lo split (+ V LDS-transpose).
__global__ __launch_bounds__(256) void gemm_kv2(
    const bf16* __restrict__ Ah, const bf16* __restrict__ Al,
    const bf16* __restrict__ B0h, const bf16* __restrict__ B0l,
    const bf16* __restrict__ B1h, const bf16* __restrict__ B1l,
    bf16* __restrict__ outKh, bf16* __restrict__ outKl,
    bf16* __restrict__ outVh, bf16* __restrict__ outVl,
    const float* __restrict__ bk, const float* __restrict__ bv)
{
  // arena: 4 staging arrays x [2 dbuf][128*32] bf16 (16 KiB each) = 64 KiB;
  // epilogue V-transpose tile [128][129] fp32 = 66048 B aliases it.
  __shared__ char arena[128 * 129 * 4] __attribute__((aligned(16)));
  bf16 (*sAh)[4096] = (bf16 (*)[4096])(arena);
  bf16 (*sBh)[4096] = (bf16 (*)[4096])(arena + 16384);
  bf16 (*sAl)[4096] = (bf16 (*)[4096])(arena + 32768);
  bf16 (*sBl)[4096] = (bf16 (*)[4096])(arena + 49152);
  const int t = threadIdx.x;
  const int K = CC;
  int lin = (blockIdx.z * 8 + blockIdx.y) * 16 + blockIdx.x;  // 256 blocks
  lin = (lin & 7) * 32 + (lin >> 3);                          // XCD swizzle
  const int n0 = (lin & 15) * 128;
  const int m0 = ((lin >> 4) & 7) * 128;
  const int kv = lin >> 7;
  const bf16* Bh = kv ? B1h : B0h;
  const bf16* Bl = kv ? B1l : B0l;
  const int srow = t >> 2, c8 = t & 3, scol = c8 * 8;
  // swizzled LDS elem offsets for this thread's two staged rows
  const int r1 = srow + 64;
  const int d0 = srow * 32 + ((c8 ^ ((srow >> 1) & 3)) * 8);
  const int d1 = r1   * 32 + ((c8 ^ ((r1   >> 1) & 3)) * 8);
  const bf16* aP  = Ah + (size_t)(m0 + srow) * K + scol;
  const bf16* bP  = Bh + (size_t)(n0 + srow) * K + scol;
  const bf16* aPl = Al + (size_t)(m0 + srow) * K + scol;
  const bf16* bPl = Bl + (size_t)(n0 + srow) * K + scol;
  const int lane = t & 63, wave = t >> 6;
  const int wm = (wave >> 1) * 64, wn = (wave & 1) * 64;
  const int quad = lane >> 4, l16 = lane & 15;
  f32x4 acc[4][4] = {};

  uint4 g0, g1, g2, g3, g4, g5, g6, g7;   // in-flight K-step (reg staging)
#define KV_LOAD(kb)                                                 \
  do {                                                              \
    g0 = *(const uint4*)(aP  + (kb));                               \
    g1 = *(const uint4*)(aP  + (kb) + (size_t)64 * K);              \
    g2 = *(const uint4*)(bP  + (kb));                               \
    g3 = *(const uint4*)(bP  + (kb) + (size_t)64 * K);              \
    g4 = *(const uint4*)(aPl + (kb));                               \
    g5 = *(const uint4*)(aPl + (kb) + (size_t)64 * K);              \
    g6 = *(const uint4*)(bPl + (kb));                               \
    g7 = *(const uint4*)(bPl + (kb) + (size_t)64 * K);              \
  } while (0)
#define KV_WRITE(buf)                                               \
  do {                                                              \
    *(uint4*)&sAh[buf][d0] = g0;  *(uint4*)&sAh[buf][d1] = g1;      \
    *(uint4*)&sBh[buf][d0] = g2;  *(uint4*)&sBh[buf][d1] = g3;      \
    *(uint4*)&sAl[buf][d0] = g4;  *(uint4*)&sAl[buf][d1] = g5;      \
    *(uint4*)&sBl[buf][d0] = g6;  *(uint4*)&sBl[buf][d1] = g7;      \
  } while (0)

  // pipeline prologue: step0 -> LDS buf0; step1 -> regs
  KV_LOAD(0);
  KV_WRITE(0);
  KV_LOAD(32);

  const int NS = K / 32;   // 64 K-steps
  for (int ci = 0; ci < NS; ci++) {
    const int cur = ci & 1;
    __syncthreads();   // closes step ci-1 reads of buf^1 (no vmcnt coupling)
    if (ci + 1 < NS) KV_WRITE(cur ^ 1);          // regs -> other buffer
    if (ci + 2 < NS) KV_LOAD((ci + 2) * 32);     // issue-early prefetch
    bf16x8 fa[4], fb[4], fal[4], fbl[4];
#pragma unroll
    for (int i = 0; i < 4; i++) {
      const int ra = wm + i * 16 + l16;
      const int rb = wn + i * 16 + l16;
      const int oa = ra * 32 + ((quad ^ ((ra >> 1) & 3)) * 8);
      const int ob = rb * 32 + ((quad ^ ((rb >> 1) & 3)) * 8);
      fa[i]  = *(const bf16x8*)&sAh[cur][oa];
      fb[i]  = *(const bf16x8*)&sBh[cur][ob];
      fal[i] = *(const bf16x8*)&sAl[cur][oa];
      fbl[i] = *(const bf16x8*)&sBl[cur][ob];
    }
#pragma unroll
    for (int mt = 0; mt < 4; mt++)
#pragma unroll
      for (int nt = 0; nt < 4; nt++) {
        f32x4 c = acc[mt][nt];
        c = mfma16(fa[mt],  fb[nt],  c);
        c = mfma16(fa[mt],  fbl[nt], c);
        c = mfma16(fal[mt], fb[nt],  c);
        acc[mt][nt] = c;
      }
  }
#undef KV_LOAD
#undef KV_WRITE

  if (kv == 0) {
    // ---- K path: bias + hi/lo split, direct store ----
#pragma unroll
    for (int mt = 0; mt < 4; mt++)
#pragma unroll
      for (int nt = 0; nt < 4; nt++)
#pragma unroll
        for (int rg = 0; rg < 4; rg++) {
          const int mr = m0 + wm + mt * 16 + quad * 4 + rg;
          const int nc = n0 + wn + nt * 16 + l16;
          const float v = acc[mt][nt][rg] + bk[nc];
          const bf16 h = (bf16)v;
          outKh[(size_t)mr * CC + nc] = h;
          outKl[(size_t)mr * CC + nc] = (bf16)(v - (float)h);
        }
  } else {
    // ---- V path: bias -> LDS tile -> transpose -> hi/lo split ----
    __syncthreads();   // all waves done with staging buffers (kv uniform/block)
    float (*tile)[129] = (float (*)[129])arena;   // aliases staging
#pragma unroll
    for (int mt = 0; mt < 4; mt++)
#pragma unroll
      for (int nt = 0; nt < 4; nt++)
#pragma unroll
        for (int rg = 0; rg < 4; rg++) {
          const int lm = wm + mt * 16 + quad * 4 + rg;
          const int ln = wn + nt * 16 + l16;
          tile[lm][ln] = acc[mt][nt][rg] + bv[n0 + ln];
        }
    __syncthreads();
    // n0 spans exactly one head (BN = CD = 128); m0 spans one b (128 | 512)
    const int h = n0 >> 7, b = m0 >> 9, lbase = m0 & (CL - 1);
    const int d = t & 127, half = t >> 7;      // 256 thr: 128 d x 2 l-halves
    const size_t orow = ((size_t)(b * CH + h) * CD + d) * CL + lbase + half * 64;
#pragma unroll
    for (int jv = 0; jv < 8; jv++) {
      bf16x8 h8, l8;
#pragma unroll
      for (int j = 0; j < 8; j++) {
        const float v = tile[half * 64 + jv * 8 + j][d];
        const bf16 hh = (bf16)v;
        h8[j] = hh;
        l8[j] = (bf16)(v - (float)hh);
      }
      *(bf16x8*)&outVh[orow + jv * 8] = h8;
      *(bf16x8*)&outVl[orow + jv * 8] = l8;
    }
  }
}

// --------- flash attention, split-bf16, MAX-FREE softmax --------------------
// R8: 1024 thr / 16 waves / 256 Q rows; ONE block per CU.  ks+vt both
// double-buffered; prefetch distance 2; ONE barrier per chunk.
__global__ __launch_bounds__(1024, 4) void attn_k(
    const bf16* __restrict__ qh, const bf16* __restrict__ ql,
    const bf16* __restrict__ kh, const bf16* __restrict__ kl,
    const bf16* __restrict__ vth, const bf16* __restrict__ vtl,
    const float* __restrict__ mask, float* __restrict__ O)
{
  // arena: ks [2][2][32][136] (34816 B) | vt [2][2][128][32] (32768 B)
  //        | ps [16][16][36] (36864 B)  = 104448 B
  __shared__ char arena[34816 + 32768 + 36864] __attribute__((aligned(16)));
  bf16 (*ksb)[2][32][136] = (bf16 (*)[2][32][136])arena;           // [dbuf][hilo]
  bf16 (*vtb)[2][128][32] = (bf16 (*)[2][128][32])(arena + 34816); // [dbuf][hilo]
  float (*ps)[16][36] = (float (*)[16][36])(arena + 34816 + 32768);
  const int t = threadIdx.x, lane = t & 63, w = t >> 6;   // w in 0..15
  const int quad = lane >> 4, l16 = lane & 15;
  int lin = (blockIdx.z * 16 + blockIdx.y) * 16 + blockIdx.x;  // (16,16,2)=512
  lin = (lin & 7) * 64 + (lin >> 3);                           // XCD swizzle
  const int n0 = (lin & 15) * 256;
  const int h  = (lin >> 4) & 15;
  const int b  = lin >> 8;
  const int bh = b * CH + h;
  const size_t qrow0 = (size_t)b * CN + n0;
  const float* mrow_base = mask + ((size_t)b * CN + n0 + w * 16 + quad * 4) * CL;

  // ---- staging-lane geometry (1024 thr: plane = hi/lo by t>>9) ----
  const int pl   = t >> 9;                       // 0 = hi, 1 = lo
  const int krow = (t >> 4) & 31, ksg = t & 15;  // K: 32 l-rows x 128 d, 16B
  const int vrow = (t >> 2) & 127, vsg = t & 3;  // V^T: 128 d-rows x 32 l, 16B
  const bf16* kPsrc = pl ? kl : kh;
  const bf16* vPsrc = pl ? vtl : vth;
  const int vc = (vsg ^ ((vrow >> 3) & 3)) * 8;  // XOR chunk swizzle (fixed)
  uint4 kr, vr;
  // chunk-0 prefetch (overlaps Q preamble)
  kr = *(const uint4*)(kPsrc + ((size_t)b * CL + krow) * CC + h * CD + ksg * 8);
  vr = *(const uint4*)(vPsrc + ((size_t)bh * CD + vrow) * CL + vsg * 8);

  // ---- Q fragments into registers (staged via arena for coalescing) ----
  bf16x8 qfh[4], qfl[4];
  {
    bf16* qs = (bf16*)arena;   // 256 rows x 136 = 69632 B (ps not yet live)
    const int row = t >> 2, sg = t & 3;
    {
      const bf16* src = qh + (qrow0 + row) * CC + h * CD + sg * 32;
      bf16* dst = qs + row * 136 + sg * 32;
#pragma unroll
      for (int j = 0; j < 4; j++) ((uint4*)dst)[j] = ((const uint4*)src)[j];
    }
    __syncthreads();
#pragma unroll
    for (int s = 0; s < 4; s++)
      qfh[s] = *(const bf16x8*)&qs[(w * 16 + l16) * 136 + s * 32 + quad * 8];
    __syncthreads();
    {
      const bf16* src = ql + (qrow0 + row) * CC + h * CD + sg * 32;
      bf16* dst = qs + row * 136 + sg * 32;
#pragma unroll
      for (int j = 0; j < 4; j++) ((uint4*)dst)[j] = ((const uint4*)src)[j];
    }
    __syncthreads();
#pragma unroll
    for (int s = 0; s < 4; s++)
      qfl[s] = *(const bf16x8*)&qs[(w * 16 + l16) * 136 + s * 32 + quad * 8];
    __syncthreads();   // qs reads done; arena now owned by ks/vt/ps
  }

  // ---- pipeline prologue: write chunk0 -> buf0; load chunk1 regs ----
  *(uint4*)&ksb[0][pl][krow][ksg * 8] = kr;
  *(uint4*)&vtb[0][pl][vrow][vc] = vr;
  kr = *(const uint4*)(kPsrc + ((size_t)b * CL + 32 + krow) * CC + h * CD + ksg * 8);
  vr = *(const uint4*)(vPsrc + ((size_t)bh * CD + vrow) * CL + 32 + vsg * 8);

  f32x4 oacc[8] = {};
  f32x4 suma = {};          // row-sum accumulator (MFMA ones-trick)
  const bf16 one = (bf16)1.0f;
  const bf16x8 ones = {one, one, one, one, one, one, one, one};
  const float isd = 0.08838834764831845f;   // np.float32(1/sqrt(128))

  for (int ci = 0; ci < CL / 32; ci++) {
    const int cur = ci & 1;
    __syncthreads();   // closes chunk ci-1 reads of buf^1; buf[cur] visible
    // ---- write-late: chunk ci+1 regs -> other buffer (overlaps compute) --
    if (ci + 1 < CL / 32) {
      *(uint4*)&ksb[cur ^ 1][pl][krow][ksg * 8] = kr;
      *(uint4*)&vtb[cur ^ 1][pl][vrow][vc] = vr;
    }
    // ---- issue-early: chunk ci+2 prefetch (full chunk of latency cover) --
    if (ci + 2 < CL / 32) {
      const int lcn = (ci + 2) * 32;
      kr = *(const uint4*)(kPsrc + ((size_t)b * CL + lcn + krow) * CC + h * CD + ksg * 8);
      vr = *(const uint4*)(vPsrc + ((size_t)bh * CD + vrow) * CL + lcn + vsg * 8);
    }
    // ---- current-chunk mask loads (QK covers the latency) ----------------
    const int lc = ci * 32;
    float mcur[2][4];
#pragma unroll
    for (int rg = 0; rg < 4; rg++) {
      const float* mrp = mrow_base + (size_t)rg * CL + lc;
      mcur[0][rg] = mrp[l16];
      mcur[1][rg] = mrp[16 + l16];
    }

    // ---- S = Q K^T (split, 3 terms), two 16x16 l-tiles -------------------
    f32x4 sacc[2] = {};
    __builtin_amdgcn_s_setprio(1);
#pragma unroll
    for (int s = 0; s < 4; s++) {
#pragma unroll
      for (int lt = 0; lt < 2; lt++) {
        bf16x8 kbh = *(const bf16x8*)&ksb[cur][0][lt * 16 + l16][s * 32 + quad * 8];
        bf16x8 kbl = *(const bf16x8*)&ksb[cur][1][lt * 16 + l16][s * 32 + quad * 8];
        sacc[lt] = mfma16(qfh[s], kbh, sacc[lt]);
        sacc[lt] = mfma16(qfh[s], kbl, sacc[lt]);
        sacc[lt] = mfma16(qfl[s], kbh, sacc[lt]);
      }
    }
    __builtin_amdgcn_s_setprio(0);

    // ---- MAX-FREE softmax: u = exp(s*isd + mask); sum rides MFMA ---------
    float u[2][4];
#pragma unroll
    for (int rg = 0; rg < 4; rg++) {
      u[0][rg] = __expf(sacc[0][rg] * isd + mcur[0][rg]);
      u[1][rg] = __expf(sacc[1][rg] * isd + mcur[1][rg]);
    }

    // ---- P: C-layout -> A-layout via wave-private LDS round-trip ---------
#pragma unroll
    for (int lt = 0; lt < 2; lt++)
#pragma unroll
      for (int rg = 0; rg < 4; rg++)
        ps[w][quad * 4 + rg][lt * 16 + l16] = u[lt][rg];
    const float4 p0 = *(const float4*)&ps[w][l16][quad * 8];
    const float4 p1 = *(const float4*)&ps[w][l16][quad * 8 + 4];
    const float pv[8] = {p0.x, p0.y, p0.z, p0.w, p1.x, p1.y, p1.z, p1.w};
    bf16x8 ph, plv;
#pragma unroll
    for (int j = 0; j < 8; j++) {
      bf16 hh = (bf16)pv[j];
      ph[j] = hh;
      plv[j] = (bf16)(pv[j] - (float)hh);
    }

    // ---- O += P V (split, 3 terms) + row-sum channel ---------------------
    suma = mfma16(ph, ones, suma);
    suma = mfma16(plv, ones, suma);
    __builtin_amdgcn_s_setprio(1);
#pragma unroll
    for (int nt = 0; nt < 8; nt++) {
      const int vrr = nt * 16 + l16;
      const int vsw = (quad ^ ((vrr >> 3) & 3)) * 8;   // match staging swizzle
      bf16x8 vbh = *(const bf16x8*)&vtb[cur][0][vrr][vsw];
      bf16x8 vbl = *(const bf16x8*)&vtb[cur][1][vrr][vsw];
      f32x4 c = oacc[nt];
      c = mfma16(ph, vbh, c);
      c = mfma16(ph, vbl, c);
      c = mfma16(plv, vbh, c);
      oacc[nt] = c;
    }
    __builtin_amdgcn_s_setprio(0);
  }

  // ---- epilogue: O / sum ----------------------------------------------------
  f32x4 inv;
#pragma unroll
  for (int rg = 0; rg < 4; rg++) inv[rg] = 1.0f / suma[rg];
#pragma unroll
  for (int nt = 0; nt < 8; nt++)
#pragma unroll
    for (int rg = 0; rg < 4; rg++) {
      const size_t row = qrow0 + w * 16 + quad * 4 + rg;
      O[row * CC + h * CD + nt * 16 + l16] = oacc[nt][rg] * inv[rg];
    }
}

// ---------------------------------------------------------------------------
extern "C" void kernel_launch(void* const* d_in, const int* in_sizes, int n_in,
                              void* d_out, int out_size, void* d_ws, size_t ws_size,
                              hipStream_t stream)
{
  (void)in_sizes; (void)n_in; (void)out_size; (void)ws_size;
  const float* x    = (const float*)d_in[0];
  const float* cond = (const float*)d_in[1];
  const float* mask = (const float*)d_in[2];
  const float* wq   = (const float*)d_in[3];
  const float* bq   = (const float*)d_in[4];
  const float* wk   = (const float*)d_in[5];
  const float* bk   = (const float*)d_in[6];
  const float* wv   = (const float*)d_in[7];
  const float* bv   = (const float*)d_in[8];
  const float* wo   = (const float*)d_in[9];
  const float* bo   = (const float*)d_in[10];
  float* out = (float*)d_out;

  char* wsb = (char*)d_ws;
  size_t off = 0;
  auto alloc = [&](size_t bytes) -> char* {
    char* p = wsb + off;
    off += (bytes + 255) & ~(size_t)255;
    return p;
  };
  // Region 1 (dead before attention; Obuf 64 MiB aliases qx..spacer)
  signed char* qx  = (signed char*)alloc((size_t)TOK * CC);  // 16 MiB
  signed char* qwq = (signed char*)alloc((size_t)CC * CC);   //  4 MiB
  bf16* ch  = (bf16*)alloc((size_t)LR * CC * 2);   //  4 MiB
  bf16* cl_ = (bf16*)alloc((size_t)LR * CC * 2);   //  4 MiB
  bf16* wkh = (bf16*)alloc((size_t)CC * CC * 2);   //  8 MiB
  bf16* wkl = (bf16*)alloc((size_t)CC * CC * 2);   //  8 MiB
  bf16* wvh = (bf16*)alloc((size_t)CC * CC * 2);   //  8 MiB
  bf16* wvl = (bf16*)alloc((size_t)CC * CC * 2);   //  8 MiB
  (void)alloc((size_t)16 << 20);                   // 16 MiB spacer (Obuf tail)
  float* Obuf = (float*)qx;                        // alias: 64 MiB over qx..spacer
  // Region 2 (live through attention)
  bf16* qhb = (bf16*)alloc((size_t)TOK * CC * 2);  // 32 MiB (later reused as qO)
  bf16* qlb = (bf16*)alloc((size_t)TOK * CC * 2);  // 32 MiB
  bf16* khb = (bf16*)alloc((size_t)LR * CC * 2);
  bf16* klb = (bf16*)alloc((size_t)LR * CC * 2);
  bf16* vth = (bf16*)alloc((size_t)LR * CC * 2);   // V^T [b,h,d,l] hi
  bf16* vtl = (bf16*)alloc((size_t)LR * CC * 2);   // V^T [b,h,d,l] lo
  signed char* qwo = (signed char*)alloc((size_t)CC * CC);
  float* sx  = (float*)alloc((size_t)TOK * 4);
  float* swq = (float*)alloc((size_t)CC * 4);
  float* swo = (float*)alloc((size_t)CC * 4);
  float* sO  = (float*)alloc((size_t)TOK * 4);
  signed char* qO = (signed char*)qhb;   // alias: qh/ql dead after attention

  const int NC = (LR * CC / 4) / 256;
  const int NW = (CC * CC / 4) / 256;
  // 1) ALL preprocessing in one dispatch: quant x/wq/wo + split cond/wk/wv
  prep_k<<<TOK + 2 * CC + NC + 2 * NW, 256, 0, stream>>>(
      x, wq, wo, cond, wk, wv, qx, qwq, qwo, sx, swq, swo,
      ch, cl_, wkh, wkl, wvh, wvl);
  // 2) Q = dequant(qx @ qwq^T) + bq, written as bf16 hi/lo split  (i8 MFMA)
  gemm_i8<1><<<dim3(CC / 128, TOK / 128, 1), 256, 0, stream>>>(
      qx, qwq, nullptr, qhb, qlb, sx, swq, bq, CC, CC);
  // 3) K/V projections: reg-staged dbuf GEMM, fused bias+split(+V transpose)
  gemm_kv2<<<dim3(CC / 128, LR / 128, 2), 256, 0, stream>>>(
      ch, cl_, wkh, wkl, wvh, wvl, khb, klb, vth, vtl, bk, bv);
  // 4) attention: 256-row Q tiles, 1024 threads, 1-barrier dbuf pipeline
  attn_k<<<dim3(CN / 256, CH, CB), 1024, 0, stream>>>(
      qhb, qlb, khb, klb, vth, vtl, mask, Obuf);
  // 5) requant O (int8 swizzled), then output projection (i8 MFMA)
  quant_rows_i8<<<TOK, 256, 0, stream>>>(Obuf, qO, sO);
  gemm_i8<0><<<dim3(CC / 128, TOK / 128, 1), 256, 0, stream>>>(
      qO, qwo, out, nullptr, nullptr, sO, swo, bo, CC, CC);
}

// Round 8
// 465.688 us; speedup vs baseline: 1.1895x; 1.0119x over previous
//
#include <hip/hip_runtime.h>
#include <cstdint>
#include <cstddef>

// ---------------------------------------------------------------------------
// QuantCrossAttention, MI355X/gfx950.  B=2 N=4096 L=512 C=2048 H=16 D=128.
// - int8 quant replicated bit-exactly (IEEE div, rintf=RNE, max-chain)
// - w8a8 GEMMs on TRUE i8 MFMA (mfma_i32_16x16x64_i8), operands XOR-swizzled
//   in GLOBAL layout so staging places them verbatim.
// - fp32 GEMMs (K/V proj, QK^T, PV) via bf16 hi/lo split, 3 MFMA terms
// R6-R12: see journal.  attn 1024-thr 1-barrier dbuf (≈122 us); gemm_kv2
// fused+reg-staged; gemm_i8 reg-staged; prep_k merged preprocessing.
// R13 (theory: gemm_i8 at 128² tile is LDS-paced — per K-step LDS ≈380-560cy
//      vs MFMA ≈330cy.  256² tile doubles accumulator reuse: 256 MFMA
//      (~1300cy) vs ~1000cy LDS => MFMA-bound.  i8 accumulation is integer-
//      exact, so the retile is bit-identical on output):
//   * gemm_i8: 256x256 tile, 512 thr / 8 waves (2m x 4n, wave tile 128x64),
//     reg-staged dist-2 pipeline, 64 KB LDS, grid 256 (1 block/CU),
//     launch_bounds(512,2).  Same dequant expression and K order.
// ---------------------------------------------------------------------------

typedef __bf16 bf16;
typedef __bf16 bf16x8 __attribute__((ext_vector_type(8)));
typedef __bf16 bf16x4 __attribute__((ext_vector_type(4)));
typedef float  f32x4  __attribute__((ext_vector_type(4)));
typedef int    i32x4  __attribute__((ext_vector_type(4)));

#define DEV __device__ __forceinline__

static constexpr int CB = 2;
static constexpr int CN = 4096;
static constexpr int CL = 512;
static constexpr int CC = 2048;
static constexpr int CH = 16;
static constexpr int CD = 128;
static constexpr int TOK = CB * CN;  // 8192 tokens
static constexpr int LR  = CB * CL;  // 1024 cond rows

DEV f32x4 mfma16(bf16x8 a, bf16x8 b, f32x4 c) {
  return __builtin_amdgcn_mfma_f32_16x16x32_bf16(a, b, c, 0, 0, 0);
}

DEV i32x4 mfma_i8(i32x4 a, i32x4 b, i32x4 c) {
  return __builtin_amdgcn_mfma_i32_16x16x64_i8(a, b, c, 0, 0, 0);
}

// --------- per-row symmetric int8 quant body (bit-exact vs np) --------------
// Output layout: within each 64B k-block, 16B unit u placed at u ^ ((row>>1)&3)
DEV void quant_row_body(const float* __restrict__ in, signed char* __restrict__ q,
                        float* __restrict__ scale, const int r, const int t)
{
  const float* x = in + (size_t)r * CC;
  const float4 v0 = ((const float4*)x)[2 * t];
  const float4 v1 = ((const float4*)x)[2 * t + 1];
  float m = fmaxf(fmaxf(fmaxf(fabsf(v0.x), fabsf(v0.y)), fmaxf(fabsf(v0.z), fabsf(v0.w))),
                  fmaxf(fmaxf(fabsf(v1.x), fabsf(v1.y)), fmaxf(fabsf(v1.z), fabsf(v1.w))));
#pragma unroll
  for (int off = 32; off > 0; off >>= 1) m = fmaxf(m, __shfl_xor(m, off));
  __shared__ float sm[4];
  if ((t & 63) == 0) sm[t >> 6] = m;
  __syncthreads();
  m = fmaxf(fmaxf(sm[0], sm[1]), fmaxf(sm[2], sm[3]));
  const float s = fmaxf(m / 127.0f, 1e-8f);   // IEEE divide: bit-matches np
  if (t == 0) scale[r] = s;
  const float a[8] = {v0.x, v0.y, v0.z, v0.w, v1.x, v1.y, v1.z, v1.w};
  int2 pk;
  int lo = 0, hi = 0;
#pragma unroll
  for (int j = 0; j < 4; j++) {
    const int b0 = (int)fminf(fmaxf(rintf(a[j]     / s), -127.f), 127.f);
    const int b1 = (int)fminf(fmaxf(rintf(a[4 + j] / s), -127.f), 127.f);
    lo |= (b0 & 255) << (8 * j);
    hi |= (b1 & 255) << (8 * j);
  }
  pk.x = lo; pk.y = hi;
  const int c0 = t * 8;
  const int f = (r >> 1) & 3;
  const int pos = (c0 & ~63) | ((((c0 >> 4) & 3) ^ f) << 4) | (c0 & 15);
  *(int2*)&q[(size_t)r * CC + pos] = pk;
}

__global__ __launch_bounds__(256) void quant_rows_i8(
    const float* __restrict__ in, signed char* __restrict__ q,
    float* __restrict__ scale)
{
  quant_row_body(in, q, scale, blockIdx.x, threadIdx.x);
}

DEV void split_body(const float* __restrict__ in, bf16* __restrict__ hi,
                    bf16* __restrict__ lo, const int blk, const int t)
{
  const size_t i = (size_t)blk * 256 + t;  // float4 index
  const float4 v = ((const float4*)in)[i];
  const float a[4] = {v.x, v.y, v.z, v.w};
  bf16x4 h4, l4;
#pragma unroll
  for (int j = 0; j < 4; j++) {
    bf16 h = (bf16)a[j];
    h4[j] = h;
    l4[j] = (bf16)(a[j] - (float)h);
  }
  ((bf16x4*)hi)[i] = h4;
  ((bf16x4*)lo)[i] = l4;
}

// --------- merged preprocessing: all quants + all splits, ONE dispatch ------
__global__ __launch_bounds__(256) void prep_k(
    const float* __restrict__ x,  const float* __restrict__ wq,
    const float* __restrict__ wo, const float* __restrict__ cond,
    const float* __restrict__ wk, const float* __restrict__ wv,
    signed char* __restrict__ qx, signed char* __restrict__ qwq,
    signed char* __restrict__ qwo,
    float* __restrict__ sx, float* __restrict__ swq, float* __restrict__ swo,
    bf16* __restrict__ ch,  bf16* __restrict__ cl_,
    bf16* __restrict__ wkh, bf16* __restrict__ wkl,
    bf16* __restrict__ wvh, bf16* __restrict__ wvl)
{
  const int t = threadIdx.x;
  const int NC = (LR * CC / 4) / 256;   // 2048 split-blocks (cond)
  const int NW = (CC * CC / 4) / 256;   // 4096 split-blocks per weight
  int blk = blockIdx.x;
  if (blk < TOK)        { quant_row_body(x,  qx,  sx,  blk, t); return; }
  blk -= TOK;
  if (blk < CC)         { quant_row_body(wq, qwq, swq, blk, t); return; }
  blk -= CC;
  if (blk < CC)         { quant_row_body(wo, qwo, swo, blk, t); return; }
  blk -= CC;
  if (blk < NC)         { split_body(cond, ch,  cl_, blk, t); return; }
  blk -= NC;
  if (blk < NW)         { split_body(wk,   wkh, wkl, blk, t); return; }
  blk -= NW;
  split_body(wv, wvh, wvl, blk, t);
}

// --------- int8 GEMM, A[M,K] * B[Nd,K]^T, both K-major, pre-swizzled --------
// R13: 256x256 tile / 512 thr / 8 waves (2m x 4n).  Reg-staged dist-2
// pipeline; XOR frag swizzle (m0,n0 = 0 mod 8 keeps the global pre-swizzle
// formula row-local).  Integer-exact => bit-identical vs 128² version.
template <int MODE>
__global__ __launch_bounds__(512, 2) void gemm_i8(
    const signed char* __restrict__ A, const signed char* __restrict__ B,
    float* __restrict__ out0, bf16* __restrict__ outH, bf16* __restrict__ outL,
    const float* __restrict__ rowS, const float* __restrict__ colS,
    const float* __restrict__ bias, const int Nd, const int K)
{
  __shared__ signed char sA[2][256 * 64] __attribute__((aligned(16)));
  __shared__ signed char sB[2][256 * 64] __attribute__((aligned(16)));
  const int t = threadIdx.x;
  int lin = blockIdx.y * 8 + blockIdx.x;           // grid = (8, 32) = 256
  lin = (lin & 7) * 32 + (lin >> 3);               // XCD-contiguous logical id
  const int m0 = (lin >> 3) * 256, n0 = (lin & 7) * 256;
  const int srow = t >> 2, scol = (t & 3) * 16;    // rows srow, srow+128; 16B
  const signed char* aP = A + (size_t)(m0 + srow) * K + scol;
  const signed char* bP = B + (size_t)(n0 + srow) * K + scol;
  const int lane = t & 63, wave = t >> 6;          // 8 waves
  const int wm = (wave >> 2) * 128, wn = (wave & 3) * 64;  // 2m x 4n
  const int quad = lane >> 4, l16 = lane & 15;
  i32x4 acc[8][4] = {};

  uint4 ga0, ga1, gb0, gb1;   // in-flight K-step (reg staging)
#define I8_LOAD(kb)                                          \
  do {                                                       \
    ga0 = *(const uint4*)(aP + (kb));                        \
    ga1 = *(const uint4*)(aP + (kb) + (size_t)128 * K);      \
    gb0 = *(const uint4*)(bP + (kb));                        \
    gb1 = *(const uint4*)(bP + (kb) + (size_t)128 * K);      \
  } while (0)
#define I8_WRITE(buf)                                        \
  do {                                                       \
    *(uint4*)&sA[buf][t * 16]        = ga0;                  \
    *(uint4*)&sA[buf][8192 + t * 16] = ga1;                  \
    *(uint4*)&sB[buf][t * 16]        = gb0;                  \
    *(uint4*)&sB[buf][8192 + t * 16] = gb1;                  \
  } while (0)

  // pipeline prologue: step0 -> LDS buf0; step1 -> regs
  I8_LOAD(0);
  I8_WRITE(0);
  I8_LOAD(64);

  const int NS = K / 64;   // 32 K-steps
  for (int ci = 0; ci < NS; ci++) {
    const int cur = ci & 1;
    __syncthreads();   // closes step ci-1 reads of buf^1 (no vmcnt coupling)
    if (ci + 1 < NS) I8_WRITE(cur ^ 1);          // regs -> other buffer
    if (ci + 2 < NS) I8_LOAD((ci + 2) * 64);     // issue-early prefetch
    i32x4 fa[8], fb[4];
#pragma unroll
    for (int i = 0; i < 8; i++) {
      const int ra = wm + i * 16 + l16;
      fa[i] = *(const i32x4*)&sA[cur][ra * 64 + (quad ^ ((ra >> 1) & 3)) * 16];
    }
#pragma unroll
    for (int j = 0; j < 4; j++) {
      const int rb = wn + j * 16 + l16;
      fb[j] = *(const i32x4*)&sB[cur][rb * 64 + (quad ^ ((rb >> 1) & 3)) * 16];
    }
#pragma unroll
    for (int mt = 0; mt < 8; mt++)
#pragma unroll
      for (int nt = 0; nt < 4; nt++)
        acc[mt][nt] = mfma_i8(fa[mt], fb[nt], acc[mt][nt]);
  }
#undef I8_LOAD
#undef I8_WRITE

  // epilogue: C/D layout col=lane&15, row=quad*4+reg (shape-determined)
#pragma unroll
  for (int mt = 0; mt < 8; mt++)
#pragma unroll
    for (int nt = 0; nt < 4; nt++)
#pragma unroll
      for (int rg = 0; rg < 4; rg++) {
        const int mr = m0 + wm + mt * 16 + quad * 4 + rg;
        const int nc = n0 + wn + nt * 16 + l16;
        const float a = (float)acc[mt][nt][rg];
        const float sc = rowS[mr] * colS[nc];   // (sx*sw) first: matches np
        const float v = a * sc + bias[nc];
        if (MODE == 0) {
          out0[(size_t)mr * Nd + nc] = v;
        } else {
          const bf16 h = (bf16)v;
          outH[(size_t)mr * Nd + nc] = h;
          outL[(size_t)mr * Nd + nc] = (bf16)(v - (float)h);
        }
      }
}

// --------- bf16-split GEMM for K/V projections, fully fused -----------------
// R10: reg-staged dist-2 pipeline + XOR unit-swizzle on LDS write and frag
// read.  Epilogue fuses bias + hi/lo split (+ V LDS-transpose).
__global__ __launch_bounds__(256) void gemm_kv2(
    const bf16* __restrict__ Ah, const bf16* __restrict__ Al,
    const bf16* __restrict__ B0h, const bf16* __restrict__ B0l,
    const bf16* __restrict__ B1h, const bf16* __restrict__ B1l,
    bf16* __restrict__ outKh, bf16* __restrict__ outKl,
    bf16* __restrict__ outVh, bf16* __restrict__ outVl,
    const float* __restrict__ bk, const float* __restrict__ bv)
{
  // arena: 4 staging arrays x [2 dbuf][128*32] bf16 (16 KiB each) = 64 KiB;
  // epilogue V-transpose tile [128][129] fp32 = 66048 B aliases it.
  __shared__ char arena[128 * 129 * 4] __attribute__((aligned(16)));
  bf16 (*sAh)[4096] = (bf16 (*)[4096])(arena);
  bf16 (*sBh)[4096] = (bf16 (*)[4096])(arena + 16384);
  bf16 (*sAl)[4096] = (bf16 (*)[4096])(arena + 32768);
  bf16 (*sBl)[4096] = (bf16 (*)[4096])(arena + 49152);
  const int t = threadIdx.x;
  const int K = CC;
  int lin = (blockIdx.z * 8 + blockIdx.y) * 16 + blockIdx.x;  // 256 blocks
  lin = (lin & 7) * 32 + (lin >> 3);                          // XCD swizzle
  const int n0 = (lin & 15) * 128;
  const int m0 = ((lin >> 4) & 7) * 128;
  const int kv = lin >> 7;
  const bf16* Bh = kv ? B1h : B0h;
  const bf16* Bl = kv ? B1l : B0l;
  const int srow = t >> 2, c8 = t & 3, scol = c8 * 8;
  // swizzled LDS elem offsets for this thread's two staged rows
  const int r1 = srow + 64;
  const int d0 = srow * 32 + ((c8 ^ ((srow >> 1) & 3)) * 8);
  const int d1 = r1   * 32 + ((c8 ^ ((r1   >> 1) & 3)) * 8);
  const bf16* aP  = Ah + (size_t)(m0 + srow) * K + scol;
  const bf16* bP  = Bh + (size_t)(n0 + srow) * K + scol;
  const bf16* aPl = Al + (size_t)(m0 + srow) * K + scol;
  const bf16* bPl = Bl + (size_t)(n0 + srow) * K + scol;
  const int lane = t & 63, wave = t >> 6;
  const int wm = (wave >> 1) * 64, wn = (wave & 1) * 64;
  const int quad = lane >> 4, l16 = lane & 15;
  f32x4 acc[4][4] = {};

  uint4 g0, g1, g2, g3, g4, g5, g6, g7;   // in-flight K-step (reg staging)
#define KV_LOAD(kb)                                                 \
  do {                                                              \
    g0 = *(const uint4*)(aP  + (kb));                               \
    g1 = *(const uint4*)(aP  + (kb) + (size_t)64 * K);              \
    g2 = *(const uint4*)(bP  + (kb));                               \
    g3 = *(const uint4*)(bP  + (kb) + (size_t)64 * K);              \
    g4 = *(const uint4*)(aPl + (kb));                               \
    g5 = *(const uint4*)(aPl + (kb) + (size_t)64 * K);              \
    g6 = *(const uint4*)(bPl + (kb));                               \
    g7 = *(const uint4*)(bPl + (kb) + (size_t)64 * K);              \
  } while (0)
#define KV_WRITE(buf)                                               \
  do {                                                              \
    *(uint4*)&sAh[buf][d0] = g0;  *(uint4*)&sAh[buf][d1] = g1;      \
    *(uint4*)&sBh[buf][d0] = g2;  *(uint4*)&sBh[buf][d1] = g3;      \
    *(uint4*)&sAl[buf][d0] = g4;  *(uint4*)&sAl[buf][d1] = g5;      \
    *(uint4*)&sBl[buf][d0] = g6;  *(uint4*)&sBl[buf][d1] = g7;      \
  } while (0)

  // pipeline prologue: step0 -> LDS buf0; step1 -> regs
  KV_LOAD(0);
  KV_WRITE(0);
  KV_LOAD(32);

  const int NS = K / 32;   // 64 K-steps
  for (int ci = 0; ci < NS; ci++) {
    const int cur = ci & 1;
    __syncthreads();   // closes step ci-1 reads of buf^1 (no vmcnt coupling)
    if (ci + 1 < NS) KV_WRITE(cur ^ 1);          // regs -> other buffer
    if (ci + 2 < NS) KV_LOAD((ci + 2) * 32);     // issue-early prefetch
    bf16x8 fa[4], fb[4], fal[4], fbl[4];
#pragma unroll
    for (int i = 0; i < 4; i++) {
      const int ra = wm + i * 16 + l16;
      const int rb = wn + i * 16 + l16;
      const int oa = ra * 32 + ((quad ^ ((ra >> 1) & 3)) * 8);
      const int ob = rb * 32 + ((quad ^ ((rb >> 1) & 3)) * 8);
      fa[i]  = *(const bf16x8*)&sAh[cur][oa];
      fb[i]  = *(const bf16x8*)&sBh[cur][ob];
      fal[i] = *(const bf16x8*)&sAl[cur][oa];
      fbl[i] = *(const bf16x8*)&sBl[cur][ob];
    }
#pragma unroll
    for (int mt = 0; mt < 4; mt++)
#pragma unroll
      for (int nt = 0; nt < 4; nt++) {
        f32x4 c = acc[mt][nt];
        c = mfma16(fa[mt],  fb[nt],  c);
        c = mfma16(fa[mt],  fbl[nt], c);
        c = mfma16(fal[mt], fb[nt],  c);
        acc[mt][nt] = c;
      }
  }
#undef KV_LOAD
#undef KV_WRITE

  if (kv == 0) {
    // ---- K path: bias + hi/lo split, direct store ----
#pragma unroll
    for (int mt = 0; mt < 4; mt++)
#pragma unroll
      for (int nt = 0; nt < 4; nt++)
#pragma unroll
        for (int rg = 0; rg < 4; rg++) {
          const int mr = m0 + wm + mt * 16 + quad * 4 + rg;
          const int nc = n0 + wn + nt * 16 + l16;
          const float v = acc[mt][nt][rg] + bk[nc];
          const bf16 h = (bf16)v;
          outKh[(size_t)mr * CC + nc] = h;
          outKl[(size_t)mr * CC + nc] = (bf16)(v - (float)h);
        }
  } else {
    // ---- V path: bias -> LDS tile -> transpose -> hi/lo split ----
    __syncthreads();   // all waves done with staging buffers (kv uniform/block)
    float (*tile)[129] = (float (*)[129])arena;   // aliases staging
#pragma unroll
    for (int mt = 0; mt < 4; mt++)
#pragma unroll
      for (int nt = 0; nt < 4; nt++)
#pragma unroll
        for (int rg = 0; rg < 4; rg++) {
          const int lm = wm + mt * 16 + quad * 4 + rg;
          const int ln = wn + nt * 16 + l16;
          tile[lm][ln] = acc[mt][nt][rg] + bv[n0 + ln];
        }
    __syncthreads();
    // n0 spans exactly one head (BN = CD = 128); m0 spans one b (128 | 512)
    const int h = n0 >> 7, b = m0 >> 9, lbase = m0 & (CL - 1);
    const int d = t & 127, half = t >> 7;      // 256 thr: 128 d x 2 l-halves
    const size_t orow = ((size_t)(b * CH + h) * CD + d) * CL + lbase + half * 64;
#pragma unroll
    for (int jv = 0; jv < 8; jv++) {
      bf16x8 h8, l8;
#pragma unroll
      for (int j = 0; j < 8; j++) {
        const float v = tile[half * 64 + jv * 8 + j][d];
        const bf16 hh = (bf16)v;
        h8[j] = hh;
        l8[j] = (bf16)(v - (float)hh);
      }
      *(bf16x8*)&outVh[orow + jv * 8] = h8;
      *(bf16x8*)&outVl[orow + jv * 8] = l8;
    }
  }
}

// --------- flash attention, split-bf16, MAX-FREE softmax --------------------
// R8: 1024 thr / 16 waves / 256 Q rows; ONE block per CU.  ks+vt both
// double-buffered; prefetch distance 2; ONE barrier per chunk.
__global__ __launch_bounds__(1024, 4) void attn_k(
    const bf16* __restrict__ qh, const bf16* __restrict__ ql,
    const bf16* __restrict__ kh, const bf16* __restrict__ kl,
    const bf16* __restrict__ vth, const bf16* __restrict__ vtl,
    const float* __restrict__ mask, float* __restrict__ O)
{
  // arena: ks [2][2][32][136] (34816 B) | vt [2][2][128][32] (32768 B)
  //        | ps [16][16][36] (36864 B)  = 104448 B
  __shared__ char arena[34816 + 32768 + 36864] __attribute__((aligned(16)));
  bf16 (*ksb)[2][32][136] = (bf16 (*)[2][32][136])arena;           // [dbuf][hilo]
  bf16 (*vtb)[2][128][32] = (bf16 (*)[2][128][32])(arena + 34816); // [dbuf][hilo]
  float (*ps)[16][36] = (float (*)[16][36])(arena + 34816 + 32768);
  const int t = threadIdx.x, lane = t & 63, w = t >> 6;   // w in 0..15
  const int quad = lane >> 4, l16 = lane & 15;
  int lin = (blockIdx.z * 16 + blockIdx.y) * 16 + blockIdx.x;  // (16,16,2)=512
  lin = (lin & 7) * 64 + (lin >> 3);                           // XCD swizzle
  const int n0 = (lin & 15) * 256;
  const int h  = (lin >> 4) & 15;
  const int b  = lin >> 8;
  const int bh = b * CH + h;
  const size_t qrow0 = (size_t)b * CN + n0;
  const float* mrow_base = mask + ((size_t)b * CN + n0 + w * 16 + quad * 4) * CL;

  // ---- staging-lane geometry (1024 thr: plane = hi/lo by t>>9) ----
  const int pl   = t >> 9;                       // 0 = hi, 1 = lo
  const int krow = (t >> 4) & 31, ksg = t & 15;  // K: 32 l-rows x 128 d, 16B
  const int vrow = (t >> 2) & 127, vsg = t & 3;  // V^T: 128 d-rows x 32 l, 16B
  const bf16* kPsrc = pl ? kl : kh;
  const bf16* vPsrc = pl ? vtl : vth;
  const int vc = (vsg ^ ((vrow >> 3) & 3)) * 8;  // XOR chunk swizzle (fixed)
  uint4 kr, vr;
  // chunk-0 prefetch (overlaps Q preamble)
  kr = *(const uint4*)(kPsrc + ((size_t)b * CL + krow) * CC + h * CD + ksg * 8);
  vr = *(const uint4*)(vPsrc + ((size_t)bh * CD + vrow) * CL + vsg * 8);

  // ---- Q fragments into registers (staged via arena for coalescing) ----
  bf16x8 qfh[4], qfl[4];
  {
    bf16* qs = (bf16*)arena;   // 256 rows x 136 = 69632 B (ps not yet live)
    const int row = t >> 2, sg = t & 3;
    {
      const bf16* src = qh + (qrow0 + row) * CC + h * CD + sg * 32;
      bf16* dst = qs + row * 136 + sg * 32;
#pragma unroll
      for (int j = 0; j < 4; j++) ((uint4*)dst)[j] = ((const uint4*)src)[j];
    }
    __syncthreads();
#pragma unroll
    for (int s = 0; s < 4; s++)
      qfh[s] = *(const bf16x8*)&qs[(w * 16 + l16) * 136 + s * 32 + quad * 8];
    __syncthreads();
    {
      const bf16* src = ql + (qrow0 + row) * CC + h * CD + sg * 32;
      bf16* dst = qs + row * 136 + sg * 32;
#pragma unroll
      for (int j = 0; j < 4; j++) ((uint4*)dst)[j] = ((const uint4*)src)[j];
    }
    __syncthreads();
#pragma unroll
    for (int s = 0; s < 4; s++)
      qfl[s] = *(const bf16x8*)&qs[(w * 16 + l16) * 136 + s * 32 + quad * 8];
    __syncthreads();   // qs reads done; arena now owned by ks/vt/ps
  }

  // ---- pipeline prologue: write chunk0 -> buf0; load chunk1 regs ----
  *(uint4*)&ksb[0][pl][krow][ksg * 8] = kr;
  *(uint4*)&vtb[0][pl][vrow][vc] = vr;
  kr = *(const uint4*)(kPsrc + ((size_t)b * CL + 32 + krow) * CC + h * CD + ksg * 8);
  vr = *(const uint4*)(vPsrc + ((size_t)bh * CD + vrow) * CL + 32 + vsg * 8);

  f32x4 oacc[8] = {};
  f32x4 suma = {};          // row-sum accumulator (MFMA ones-trick)
  const bf16 one = (bf16)1.0f;
  const bf16x8 ones = {one, one, one, one, one, one, one, one};
  const float isd = 0.08838834764831845f;   // np.float32(1/sqrt(128))

  for (int ci = 0; ci < CL / 32; ci++) {
    const int cur = ci & 1;
    __syncthreads();   // closes chunk ci-1 reads of buf^1; buf[cur] visible
    // ---- write-late: chunk ci+1 regs -> other buffer (overlaps compute) --
    if (ci + 1 < CL / 32) {
      *(uint4*)&ksb[cur ^ 1][pl][krow][ksg * 8] = kr;
      *(uint4*)&vtb[cur ^ 1][pl][vrow][vc] = vr;
    }
    // ---- issue-early: chunk ci+2 prefetch (full chunk of latency cover) --
    if (ci + 2 < CL / 32) {
      const int lcn = (ci + 2) * 32;
      kr = *(const uint4*)(kPsrc + ((size_t)b * CL + lcn + krow) * CC + h * CD + ksg * 8);
      vr = *(const uint4*)(vPsrc + ((size_t)bh * CD + vrow) * CL + lcn + vsg * 8);
    }
    // ---- current-chunk mask loads (QK covers the latency) ----------------
    const int lc = ci * 32;
    float mcur[2][4];
#pragma unroll
    for (int rg = 0; rg < 4; rg++) {
      const float* mrp = mrow_base + (size_t)rg * CL + lc;
      mcur[0][rg] = mrp[l16];
      mcur[1][rg] = mrp[16 + l16];
    }

    // ---- S = Q K^T (split, 3 terms), two 16x16 l-tiles -------------------
    f32x4 sacc[2] = {};
    __builtin_amdgcn_s_setprio(1);
#pragma unroll
    for (int s = 0; s < 4; s++) {
#pragma unroll
      for (int lt = 0; lt < 2; lt++) {
        bf16x8 kbh = *(const bf16x8*)&ksb[cur][0][lt * 16 + l16][s * 32 + quad * 8];
        bf16x8 kbl = *(const bf16x8*)&ksb[cur][1][lt * 16 + l16][s * 32 + quad * 8];
        sacc[lt] = mfma16(qfh[s], kbh, sacc[lt]);
        sacc[lt] = mfma16(qfh[s], kbl, sacc[lt]);
        sacc[lt] = mfma16(qfl[s], kbh, sacc[lt]);
      }
    }
    __builtin_amdgcn_s_setprio(0);

    // ---- MAX-FREE softmax: u = exp(s*isd + mask); sum rides MFMA ---------
    float u[2][4];
#pragma unroll
    for (int rg = 0; rg < 4; rg++) {
      u[0][rg] = __expf(sacc[0][rg] * isd + mcur[0][rg]);
      u[1][rg] = __expf(sacc[1][rg] * isd + mcur[1][rg]);
    }

    // ---- P: C-layout -> A-layout via wave-private LDS round-trip ---------
#pragma unroll
    for (int lt = 0; lt < 2; lt++)
#pragma unroll
      for (int rg = 0; rg < 4; rg++)
        ps[w][quad * 4 + rg][lt * 16 + l16] = u[lt][rg];
    const float4 p0 = *(const float4*)&ps[w][l16][quad * 8];
    const float4 p1 = *(const float4*)&ps[w][l16][quad * 8 + 4];
    const float pv[8] = {p0.x, p0.y, p0.z, p0.w, p1.x, p1.y, p1.z, p1.w};
    bf16x8 ph, plv;
#pragma unroll
    for (int j = 0; j < 8; j++) {
      bf16 hh = (bf16)pv[j];
      ph[j] = hh;
      plv[j] = (bf16)(pv[j] - (float)hh);
    }

    // ---- O += P V (split, 3 terms) + row-sum channel ---------------------
    suma = mfma16(ph, ones, suma);
    suma = mfma16(plv, ones, suma);
    __builtin_amdgcn_s_setprio(1);
#pragma unroll
    for (int nt = 0; nt < 8; nt++) {
      const int vrr = nt * 16 + l16;
      const int vsw = (quad ^ ((vrr >> 3) & 3)) * 8;   // match staging swizzle
      bf16x8 vbh = *(const bf16x8*)&vtb[cur][0][vrr][vsw];
      bf16x8 vbl = *(const bf16x8*)&vtb[cur][1][vrr][vsw];
      f32x4 c = oacc[nt];
      c = mfma16(ph, vbh, c);
      c = mfma16(ph, vbl, c);
      c = mfma16(plv, vbh, c);
      oacc[nt] = c;
    }
    __builtin_amdgcn_s_setprio(0);
  }

  // ---- epilogue: O / sum ----------------------------------------------------
  f32x4 inv;
#pragma unroll
  for (int rg = 0; rg < 4; rg++) inv[rg] = 1.0f / suma[rg];
#pragma unroll
  for (int nt = 0; nt < 8; nt++)
#pragma unroll
    for (int rg = 0; rg < 4; rg++) {
      const size_t row = qrow0 + w * 16 + quad * 4 + rg;
      O[row * CC + h * CD + nt * 16 + l16] = oacc[nt][rg] * inv[rg];
    }
}

// ---------------------------------------------------------------------------
extern "C" void kernel_launch(void* const* d_in, const int* in_sizes, int n_in,
                              void* d_out, int out_size, void* d_ws, size_t ws_size,
                              hipStream_t stream)
{
  (void)in_sizes; (void)n_in; (void)out_size; (void)ws_size;
  const float* x    = (const float*)d_in[0];
  const float* cond = (const float*)d_in[1];
  const float* mask = (const float*)d_in[2];
  const float* wq   = (const float*)d_in[3];
  const float* bq   = (const float*)d_in[4];
  const float* wk   = (const float*)d_in[5];
  const float* bk   = (const float*)d_in[6];
  const float* wv   = (const float*)d_in[7];
  const float* bv   = (const float*)d_in[8];
  const float* wo   = (const float*)d_in[9];
  const float* bo   = (const float*)d_in[10];
  float* out = (float*)d_out;

  char* wsb = (char*)d_ws;
  size_t off = 0;
  auto alloc = [&](size_t bytes) -> char* {
    char* p = wsb + off;
    off += (bytes + 255) & ~(size_t)255;
    return p;
  };
  // Region 1 (dead before attention; Obuf 64 MiB aliases qx..spacer)
  signed char* qx  = (signed char*)alloc((size_t)TOK * CC);  // 16 MiB
  signed char* qwq = (signed char*)alloc((size_t)CC * CC);   //  4 MiB
  bf16* ch  = (bf16*)alloc((size_t)LR * CC * 2);   //  4 MiB
  bf16* cl_ = (bf16*)alloc((size_t)LR * CC * 2);   //  4 MiB
  bf16* wkh = (bf16*)alloc((size_t)CC * CC * 2);   //  8 MiB
  bf16* wkl = (bf16*)alloc((size_t)CC * CC * 2);   //  8 MiB
  bf16* wvh = (bf16*)alloc((size_t)CC * CC * 2);   //  8 MiB
  bf16* wvl = (bf16*)alloc((size_t)CC * CC * 2);   //  8 MiB
  (void)alloc((size_t)16 << 20);                   // 16 MiB spacer (Obuf tail)
  float* Obuf = (float*)qx;                        // alias: 64 MiB over qx..spacer
  // Region 2 (live through attention)
  bf16* qhb = (bf16*)alloc((size_t)TOK * CC * 2);  // 32 MiB (later reused as qO)
  bf16* qlb = (bf16*)alloc((size_t)TOK * CC * 2);  // 32 MiB
  bf16* khb = (bf16*)alloc((size_t)LR * CC * 2);
  bf16* klb = (bf16*)alloc((size_t)LR * CC * 2);
  bf16* vth = (bf16*)alloc((size_t)LR * CC * 2);   // V^T [b,h,d,l] hi
  bf16* vtl = (bf16*)alloc((size_t)LR * CC * 2);   // V^T [b,h,d,l] lo
  signed char* qwo = (signed char*)alloc((size_t)CC * CC);
  float* sx  = (float*)alloc((size_t)TOK * 4);
  float* swq = (float*)alloc((size_t)CC * 4);
  float* swo = (float*)alloc((size_t)CC * 4);
  float* sO  = (float*)alloc((size_t)TOK * 4);
  signed char* qO = (signed char*)qhb;   // alias: qh/ql dead after attention

  const int NC = (LR * CC / 4) / 256;
  const int NW = (CC * CC / 4) / 256;
  // 1) ALL preprocessing in one dispatch: quant x/wq/wo + split cond/wk/wv
  prep_k<<<TOK + 2 * CC + NC + 2 * NW, 256, 0, stream>>>(
      x, wq, wo, cond, wk, wv, qx, qwq, qwo, sx, swq, swo,
      ch, cl_, wkh, wkl, wvh, wvl);
  // 2) Q = dequant(qx @ qwq^T) + bq, written as bf16 hi/lo split  (i8 MFMA)
  gemm_i8<1><<<dim3(CC / 256, TOK / 256, 1), 512, 0, stream>>>(
      qx, qwq, nullptr, qhb, qlb, sx, swq, bq, CC, CC);
  // 3) K/V projections: reg-staged dbuf GEMM, fused bias+split(+V transpose)
  gemm_kv2<<<dim3(CC / 128, LR / 128, 2), 256, 0, stream>>>(
      ch, cl_, wkh, wkl, wvh, wvl, khb, klb, vth, vtl, bk, bv);
  // 4) attention: 256-row Q tiles, 1024 threads, 1-barrier dbuf pipeline
  attn_k<<<dim3(CN / 256, CH, CB), 1024, 0, stream>>>(
      qhb, qlb, khb, klb, vth, vtl, mask, Obuf);
  // 5) requant O (int8 swizzled), then output projection (i8 MFMA)
  quant_rows_i8<<<TOK, 256, 0, stream>>>(Obuf, qO, sO);
  gemm_i8<0><<<dim3(CC / 256, TOK / 256, 1), 512, 0, stream>>>(
      qO, qwo, out, nullptr, nullptr, sO, swo, bo, CC, CC);
}